// Round 1
// baseline (626.921 us; speedup 1.0000x reference)
//
#include <hip/hip_runtime.h>
#include <math.h>

#define HWp 4096
#define Wd 64
#define Hd 64
#define Cc 96
#define Bb 4
#define COP 176   // padded offset-conv output channels (166 real)
#define Oo 192
#define C3 288

// ---------------- workspace layout (in floats) ----------------
// WT    : [864][176]  transposed concat offset weights      @ 0
// WPT   : [288][192]  transposed pointwise weights          @ 152064
// wdwf  : [96*9 | 96*25 | 96*49] depthwise weights          @ 207360
// bcat  : [176] offset-conv bias                            @ 215328
// sbr   : [288] branch BN scale                             @ 215504
// hbr   : [288] branch BN shift                             @ 215792
// spw   : [192] pw BN scale                                 @ 216080
// hpw   : [192] pw BN shift                                 @ 216272
// off   : [4][176][4096] offset conv output                 @ 216464
// ybuf  : [4][288][4096] branch outputs (post BN+ReLU)      @ 3100048
#define OFF_WT    0
#define OFF_WPT   152064
#define OFF_WDW   207360
#define OFF_BCAT  215328
#define OFF_SBR   215504
#define OFF_HBR   215792
#define OFF_SPW   216080
#define OFF_HPW   216272
#define OFF_OFF   216464
#define OFF_Y     3100048
#define PREP_N    216464

__global__ __launch_bounds__(256) void prep_kernel(
    const float* __restrict__ w3, const float* __restrict__ b3, const float* __restrict__ dw3,
    const float* __restrict__ g3, const float* __restrict__ be3, const float* __restrict__ m3, const float* __restrict__ v3,
    const float* __restrict__ w5, const float* __restrict__ b5, const float* __restrict__ dw5,
    const float* __restrict__ g5, const float* __restrict__ be5, const float* __restrict__ m5, const float* __restrict__ v5,
    const float* __restrict__ w7, const float* __restrict__ b7, const float* __restrict__ dw7,
    const float* __restrict__ g7, const float* __restrict__ be7, const float* __restrict__ m7, const float* __restrict__ v7,
    const float* __restrict__ wpw,
    const float* __restrict__ gp, const float* __restrict__ bp, const float* __restrict__ mp, const float* __restrict__ vp,
    float* __restrict__ ws)
{
    int i = blockIdx.x * 256 + threadIdx.x;
    // WT [864][176]
    if (i < 152064) {
        int kidx = i / COP, co = i % COP;
        float v = 0.f;
        if (co < 166) {
            if (co < 18)       v = w3[co * 864 + kidx];
            else if (co < 68)  v = w5[(co - 18) * 864 + kidx];
            else               v = w7[(co - 68) * 864 + kidx];
        }
        ws[OFF_WT + i] = v;
        return;
    }
    int j = i - 152064;
    // WPT [288][192]
    if (j < 55296) {
        int c = j / Oo, o = j % Oo;
        ws[OFF_WPT + j] = wpw[o * C3 + c];
        return;
    }
    j -= 55296;
    // wdwf concat copy
    if (j < 7968) {
        float v;
        if (j < 864)        v = dw3[j];
        else if (j < 3264)  v = dw5[j - 864];
        else                v = dw7[j - 3264];
        ws[OFF_WDW + j] = v;
        return;
    }
    j -= 7968;
    // bcat [176]
    if (j < COP) {
        float v = 0.f;
        if (j < 18)       v = b3[j];
        else if (j < 68)  v = b5[j - 18];
        else if (j < 166) v = b7[j - 68];
        ws[OFF_BCAT + j] = v;
        return;
    }
    j -= COP;
    // sbr [288]
    if (j < C3) {
        int ks = j / Cc, c = j % Cc;
        const float* g = (ks == 0) ? g3 : (ks == 1) ? g5 : g7;
        const float* v = (ks == 0) ? v3 : (ks == 1) ? v5 : v7;
        ws[OFF_SBR + j] = g[c] / sqrtf(v[c] + 1e-5f);
        return;
    }
    j -= C3;
    // hbr [288]
    if (j < C3) {
        int ks = j / Cc, c = j % Cc;
        const float* g = (ks == 0) ? g3 : (ks == 1) ? g5 : g7;
        const float* v = (ks == 0) ? v3 : (ks == 1) ? v5 : v7;
        const float* be = (ks == 0) ? be3 : (ks == 1) ? be5 : be7;
        const float* m = (ks == 0) ? m3 : (ks == 1) ? m5 : m7;
        float inv = g[c] / sqrtf(v[c] + 1e-5f);
        ws[OFF_HBR + j] = be[c] - m[c] * inv;
        return;
    }
    j -= C3;
    // spw [192]
    if (j < Oo) {
        ws[OFF_SPW + j] = gp[j] / sqrtf(vp[j] + 1e-5f);
        return;
    }
    j -= Oo;
    // hpw [192]
    if (j < Oo) {
        float inv = gp[j] / sqrtf(vp[j] + 1e-5f);
        ws[OFF_HPW + j] = bp[j] - mp[j] * inv;
        return;
    }
}

// Fused 3x offset conv as one implicit GEMM: out[176][p] = WT^T @ patch
__global__ __launch_bounds__(256) void offconv_kernel(
    const float* __restrict__ x, const float* __restrict__ ws, float* __restrict__ off)
{
    const float* WT = ws + OFF_WT;
    const float* bcat = ws + OFF_BCAT;
    const int tid = threadIdx.x;
    const int p = blockIdx.x * 256 + tid;
    const int h = p >> 6, w = p & 63;
    const int co0 = blockIdx.y * 16;
    const int b = blockIdx.z;

    float acc[16];
#pragma unroll
    for (int j = 0; j < 16; ++j) acc[j] = bcat[co0 + j];

    const float* xb = x + (size_t)b * Cc * HWp;
    for (int c = 0; c < Cc; ++c) {
        const float* xc = xb + c * HWp;
        const float* wr = WT + (c * 9) * COP + co0;
#pragma unroll
        for (int ky = 0; ky < 3; ++ky) {
            int yy = h + ky - 1;
            bool rok = ((unsigned)yy < 64u);
            int ycl = min(max(yy, 0), 63);
#pragma unroll
            for (int kx = 0; kx < 3; ++kx) {
                int xx = w + kx - 1;
                bool ok = rok && ((unsigned)xx < 64u);
                int xcl = min(max(xx, 0), 63);
                float v = xc[(ycl << 6) + xcl];
                v = ok ? v : 0.f;
                const float* wrow = wr + (ky * 3 + kx) * COP;
#pragma unroll
                for (int j = 0; j < 16; ++j) acc[j] += wrow[j] * v;
            }
        }
    }
    float* ob = off + ((size_t)b * COP + co0) * HWp + p;
#pragma unroll
    for (int j = 0; j < 16; ++j) ob[(size_t)j * HWp] = acc[j];
}

// Deformable bilinear sampling + depthwise reduce + BN + ReLU
__global__ __launch_bounds__(256) void sampdw_kernel(
    const float* __restrict__ x, const float* __restrict__ ws, float* __restrict__ ybuf)
{
    const float* off = ws + OFF_OFF;
    const float* wdwf = ws + OFF_WDW;
    const float* sbr = ws + OFF_SBR;
    const float* hbr = ws + OFF_HBR;

    const int tid = threadIdx.x;
    const int p = blockIdx.x * 256 + tid;
    const int hh = p >> 6, wwp = p & 63;
    const int sel = blockIdx.y;          // 0..17
    const int ksel = sel / 6, cch = sel % 6;
    const int b = blockIdx.z;
    const int k = 3 + 2 * ksel;
    const int K2 = k * k;
    const int r = (k - 1) >> 1;
    const int tb = (ksel == 0) ? 0 : ((ksel == 1) ? 18 : 68);
    const int wb = (ksel == 0) ? 0 : ((ksel == 1) ? 864 : 3264);
    const int c0 = cch * 16;

    float acc[16];
#pragma unroll
    for (int j = 0; j < 16; ++j) acc[j] = 0.f;

    const float* offb = off + ((size_t)b * COP + tb) * HWp + p;
    const float* xb = x + ((size_t)b * Cc + c0) * HWp;

    int ky = -r, kx = -r;
    for (int t = 0; t < K2; ++t) {
        float dy = offb[(size_t)t * HWp];
        float dx = offb[(size_t)(K2 + t) * HWp];
        float py = (float)(hh + ky) + dy;
        float px = (float)(wwp + kx) + dx;
        py = fminf(fmaxf(py, 0.f), 63.f);
        px = fminf(fmaxf(px, 0.f), 63.f);
        float fy = floorf(py), fx = floorf(px);
        int y0 = (int)fy, x0 = (int)fx;
        float wy = py - fy, wx = px - fx;
        int y1 = min(y0 + 1, 63), x1 = min(x0 + 1, 63);
        int o00 = (y0 << 6) + x0, o01 = (y0 << 6) + x1;
        int o10 = (y1 << 6) + x0, o11 = (y1 << 6) + x1;
        float w11 = wy * wx;
        float w10 = wy - w11;
        float w01 = wx - w11;
        float w00 = 1.f - wy - wx + w11;
        const float* wd = wdwf + wb + t;
#pragma unroll
        for (int c = 0; c < 16; ++c) {
            const float* xc = xb + c * HWp;
            float v = w00 * xc[o00] + w01 * xc[o01] + w10 * xc[o10] + w11 * xc[o11];
            acc[c] += wd[(c0 + c) * K2] * v;
        }
        ++kx;
        if (kx > r) { kx = -r; ++ky; }
    }

    const int cb = ksel * Cc + c0;
    float* yb = ybuf + ((size_t)b * C3 + cb) * HWp + p;
#pragma unroll
    for (int j = 0; j < 16; ++j) {
        float v = acc[j] * sbr[cb + j] + hbr[cb + j];
        yb[(size_t)j * HWp] = fmaxf(v, 0.f);
    }
}

// Pointwise 288->192 + BN + ReLU
__global__ __launch_bounds__(256) void pwconv_kernel(
    const float* __restrict__ ws_y, const float* __restrict__ ws, float* __restrict__ out)
{
    const float* WPT = ws + OFF_WPT;
    const float* spw = ws + OFF_SPW;
    const float* hpw = ws + OFF_HPW;

    const int tid = threadIdx.x;
    const int p = blockIdx.x * 256 + tid;
    const int o0 = blockIdx.y * 16;
    const int b = blockIdx.z;

    float acc[16];
#pragma unroll
    for (int j = 0; j < 16; ++j) acc[j] = 0.f;

    const float* yb = ws_y + (size_t)b * C3 * HWp + p;
    for (int c = 0; c < C3; ++c) {
        float v = yb[(size_t)c * HWp];
        const float* wrow = WPT + c * Oo + o0;
#pragma unroll
        for (int j = 0; j < 16; ++j) acc[j] += wrow[j] * v;
    }
    float* ob = out + ((size_t)b * Oo + o0) * HWp + p;
#pragma unroll
    for (int j = 0; j < 16; ++j) {
        float v = acc[j] * spw[o0 + j] + hpw[o0 + j];
        ob[(size_t)j * HWp] = fmaxf(v, 0.f);
    }
}

extern "C" void kernel_launch(void* const* d_in, const int* in_sizes, int n_in,
                              void* d_out, int out_size, void* d_ws, size_t ws_size,
                              hipStream_t stream)
{
    const float* x     = (const float*)d_in[0];
    const float* w3    = (const float*)d_in[1];
    const float* b3    = (const float*)d_in[2];
    const float* dw3   = (const float*)d_in[3];
    const float* g3    = (const float*)d_in[4];
    const float* be3   = (const float*)d_in[5];
    const float* m3    = (const float*)d_in[6];
    const float* v3    = (const float*)d_in[7];
    const float* w5    = (const float*)d_in[8];
    const float* b5    = (const float*)d_in[9];
    const float* dw5   = (const float*)d_in[10];
    const float* g5    = (const float*)d_in[11];
    const float* be5   = (const float*)d_in[12];
    const float* m5    = (const float*)d_in[13];
    const float* v5    = (const float*)d_in[14];
    const float* w7    = (const float*)d_in[15];
    const float* b7    = (const float*)d_in[16];
    const float* dw7   = (const float*)d_in[17];
    const float* g7    = (const float*)d_in[18];
    const float* be7   = (const float*)d_in[19];
    const float* m7    = (const float*)d_in[20];
    const float* v7    = (const float*)d_in[21];
    const float* wpw   = (const float*)d_in[22];
    const float* gp    = (const float*)d_in[23];
    const float* bp    = (const float*)d_in[24];
    const float* mp    = (const float*)d_in[25];
    const float* vp    = (const float*)d_in[26];

    float* ws = (float*)d_ws;
    float* out = (float*)d_out;

    // 1) prep: repack weights, fold BN
    {
        dim3 grid((PREP_N + 255) / 256);
        prep_kernel<<<grid, 256, 0, stream>>>(
            w3, b3, dw3, g3, be3, m3, v3,
            w5, b5, dw5, g5, be5, m5, v5,
            w7, b7, dw7, g7, be7, m7, v7,
            wpw, gp, bp, mp, vp, ws);
    }
    // 2) fused offset conv (all three k) -> off buffer
    {
        dim3 grid(HWp / 256, COP / 16, Bb);
        offconv_kernel<<<grid, 256, 0, stream>>>(x, ws, ws + OFF_OFF);
    }
    // 3) deformable sampling + depthwise + BN + ReLU -> ybuf
    {
        dim3 grid(HWp / 256, 18, Bb);
        sampdw_kernel<<<grid, 256, 0, stream>>>(x, ws, ws + OFF_Y);
    }
    // 4) pointwise + BN + ReLU -> out
    {
        dim3 grid(HWp / 256, Oo / 16, Bb);
        pwconv_kernel<<<grid, 256, 0, stream>>>(ws + OFF_Y, ws, out);
    }
}

// Round 2
// 480.189 us; speedup vs baseline: 1.3056x; 1.3056x over previous
//
#include <hip/hip_runtime.h>
#include <math.h>

#define HWp 4096
#define Wd 64
#define Hd 64
#define Cc 96
#define Bb 4
#define COP 176   // padded offset-conv output channels (166 real)
#define Oo 192
#define C3 288

// ---------------- workspace layout (in floats) ----------------
#define OFF_WT    0           // [864][176]
#define OFF_WPT   152064      // [288][192]
#define OFF_WDW   207360      // [96*9|96*25|96*49]
#define OFF_BCAT  215328      // [176]
#define OFF_SBR   215504      // [288]
#define OFF_HBR   215792      // [288]
#define OFF_SPW   216080      // [192]
#define OFF_HPW   216272      // [192]
#define OFF_WDWT  216464      // [3][49][96] transposed dw weights (zero-padded taps)
#define OFF_OFF   230576      // [4][176][4096]
#define OFF_Y     3114160     // [4][288][4096]
#define OFF_XT    7832752     // [4][4096][96] NHWC transposed x
#define PREP_N    230576

__global__ __launch_bounds__(256) void prep_kernel(
    const float* __restrict__ w3, const float* __restrict__ b3, const float* __restrict__ dw3,
    const float* __restrict__ g3, const float* __restrict__ be3, const float* __restrict__ m3, const float* __restrict__ v3,
    const float* __restrict__ w5, const float* __restrict__ b5, const float* __restrict__ dw5,
    const float* __restrict__ g5, const float* __restrict__ be5, const float* __restrict__ m5, const float* __restrict__ v5,
    const float* __restrict__ w7, const float* __restrict__ b7, const float* __restrict__ dw7,
    const float* __restrict__ g7, const float* __restrict__ be7, const float* __restrict__ m7, const float* __restrict__ v7,
    const float* __restrict__ wpw,
    const float* __restrict__ gp, const float* __restrict__ bp, const float* __restrict__ mp, const float* __restrict__ vp,
    float* __restrict__ ws)
{
    int i = blockIdx.x * 256 + threadIdx.x;
    if (i < 152064) {                       // WT [864][176]
        int kidx = i / COP, co = i % COP;
        float v = 0.f;
        if (co < 166) {
            if (co < 18)       v = w3[co * 864 + kidx];
            else if (co < 68)  v = w5[(co - 18) * 864 + kidx];
            else               v = w7[(co - 68) * 864 + kidx];
        }
        ws[OFF_WT + i] = v;
        return;
    }
    int j = i - 152064;
    if (j < 55296) {                        // WPT [288][192]
        int c = j / Oo, o = j % Oo;
        ws[OFF_WPT + j] = wpw[o * C3 + c];
        return;
    }
    j -= 55296;
    if (j < 7968) {                         // wdwf concat
        float v;
        if (j < 864)        v = dw3[j];
        else if (j < 3264)  v = dw5[j - 864];
        else                v = dw7[j - 3264];
        ws[OFF_WDW + j] = v;
        return;
    }
    j -= 7968;
    if (j < COP) {                          // bcat
        float v = 0.f;
        if (j < 18)       v = b3[j];
        else if (j < 68)  v = b5[j - 18];
        else if (j < 166) v = b7[j - 68];
        ws[OFF_BCAT + j] = v;
        return;
    }
    j -= COP;
    if (j < C3) {                           // sbr
        int ks = j / Cc, c = j % Cc;
        const float* g = (ks == 0) ? g3 : (ks == 1) ? g5 : g7;
        const float* v = (ks == 0) ? v3 : (ks == 1) ? v5 : v7;
        ws[OFF_SBR + j] = g[c] / sqrtf(v[c] + 1e-5f);
        return;
    }
    j -= C3;
    if (j < C3) {                           // hbr
        int ks = j / Cc, c = j % Cc;
        const float* g = (ks == 0) ? g3 : (ks == 1) ? g5 : g7;
        const float* v = (ks == 0) ? v3 : (ks == 1) ? v5 : v7;
        const float* be = (ks == 0) ? be3 : (ks == 1) ? be5 : be7;
        const float* m = (ks == 0) ? m3 : (ks == 1) ? m5 : m7;
        float inv = g[c] / sqrtf(v[c] + 1e-5f);
        ws[OFF_HBR + j] = be[c] - m[c] * inv;
        return;
    }
    j -= C3;
    if (j < Oo) {                           // spw
        ws[OFF_SPW + j] = gp[j] / sqrtf(vp[j] + 1e-5f);
        return;
    }
    j -= Oo;
    if (j < Oo) {                           // hpw
        float inv = gp[j] / sqrtf(vp[j] + 1e-5f);
        ws[OFF_HPW + j] = bp[j] - mp[j] * inv;
        return;
    }
    j -= Oo;
    if (j < 14112) {                        // wdwT [3][49][96]
        int ksel = j / 4704, rem = j % 4704;
        int t = rem / 96, c = rem % 96;
        int K2 = (ksel == 0) ? 9 : (ksel == 1) ? 25 : 49;
        const float* dw = (ksel == 0) ? dw3 : (ksel == 1) ? dw5 : dw7;
        ws[OFF_WDWT + j] = (t < K2) ? dw[c * K2 + t] : 0.f;
        return;
    }
}

// NCHW -> NHWC transpose of x into workspace
__global__ __launch_bounds__(256) void transpose_kernel(
    const float* __restrict__ x, float* __restrict__ xT)
{
    const int tid = threadIdx.x;
    const int p = blockIdx.x * 256 + tid;
    const int c0 = blockIdx.y * 16;
    const int b = blockIdx.z;
    float tmp[16];
#pragma unroll
    for (int c = 0; c < 16; ++c)
        tmp[c] = x[((size_t)(b * Cc + c0 + c) << 12) + p];
    float* dst = xT + ((size_t)(b << 12) + p) * 96 + c0;
#pragma unroll
    for (int i = 0; i < 4; ++i) {
        float4 v = make_float4(tmp[4 * i], tmp[4 * i + 1], tmp[4 * i + 2], tmp[4 * i + 3]);
        *(float4*)(dst + 4 * i) = v;
    }
}

// Fused 3x offset conv as one implicit GEMM
__global__ __launch_bounds__(256) void offconv_kernel(
    const float* __restrict__ x, const float* __restrict__ ws, float* __restrict__ off)
{
    const float* WT = ws + OFF_WT;
    const float* bcat = ws + OFF_BCAT;
    const int tid = threadIdx.x;
    const int p = blockIdx.x * 256 + tid;
    const int h = p >> 6, w = p & 63;
    const int co0 = blockIdx.y * 16;
    const int b = blockIdx.z;

    float acc[16];
#pragma unroll
    for (int j = 0; j < 16; ++j) acc[j] = bcat[co0 + j];

    const float* xb = x + (size_t)b * Cc * HWp;
    for (int c = 0; c < Cc; ++c) {
        const float* xc = xb + c * HWp;
        const float* wr = WT + (c * 9) * COP + co0;
#pragma unroll
        for (int ky = 0; ky < 3; ++ky) {
            int yy = h + ky - 1;
            bool rok = ((unsigned)yy < 64u);
            int ycl = min(max(yy, 0), 63);
#pragma unroll
            for (int kx = 0; kx < 3; ++kx) {
                int xx = w + kx - 1;
                bool ok = rok && ((unsigned)xx < 64u);
                int xcl = min(max(xx, 0), 63);
                float v = xc[(ycl << 6) + xcl];
                v = ok ? v : 0.f;
                const float* wrow = wr + (ky * 3 + kx) * COP;
#pragma unroll
                for (int j = 0; j < 16; ++j) acc[j] += wrow[j] * v;
            }
        }
    }
    float* ob = off + ((size_t)b * COP + co0) * HWp + p;
#pragma unroll
    for (int j = 0; j < 16; ++j) ob[(size_t)j * HWp] = acc[j];
}

// Deformable bilinear sampling + depthwise + BN + ReLU, NHWC gather
template<int K, int CT>
__device__ __forceinline__ void samp_body(
    int c0, int ksel, int tb,
    const float* __restrict__ xT, const float* __restrict__ ws, float* __restrict__ ybuf)
{
    constexpr int K2 = K * K;
    constexpr int R = (K - 1) / 2;
    constexpr int NC4 = CT / 4;
    const int tid = threadIdx.x;
    const int p = blockIdx.x * 256 + tid;
    const int hh = p >> 6, wwp = p & 63;
    const int b = blockIdx.z;

    const float* offb = ws + OFF_OFF + ((size_t)b * COP + tb) * HWp + p;
    const float* wdT  = ws + OFF_WDWT + ksel * 4704 + c0;
    const float* xb   = xT + (((size_t)b) << 12) * 96;

    float4 acc[NC4];
#pragma unroll
    for (int i = 0; i < NC4; ++i) acc[i] = make_float4(0.f, 0.f, 0.f, 0.f);

#pragma unroll 2
    for (int t = 0; t < K2; ++t) {
        int tq = t / K;
        int ky = tq - R;
        int kx = t - tq * K - R;
        float dy = offb[(size_t)t * HWp];
        float dx = offb[(size_t)(K2 + t) * HWp];
        float py = fminf(fmaxf((float)(hh + ky) + dy, 0.f), 63.f);
        float px = fminf(fmaxf((float)(wwp + kx) + dx, 0.f), 63.f);
        float fy = floorf(py), fx = floorf(px);
        int y0 = (int)fy, x0 = (int)fx;
        float wy = py - fy, wx = px - fx;
        int y1 = min(y0 + 1, 63), x1 = min(x0 + 1, 63);
        float w11 = wy * wx;
        float w10 = wy - w11;
        float w01 = wx - w11;
        float w00 = 1.f - wy - wx + w11;
        const float* p00 = xb + (size_t)((y0 << 6) + x0) * 96 + c0;
        const float* p01 = xb + (size_t)((y0 << 6) + x1) * 96 + c0;
        const float* p10 = xb + (size_t)((y1 << 6) + x0) * 96 + c0;
        const float* p11 = xb + (size_t)((y1 << 6) + x1) * 96 + c0;
        const float* wdr = wdT + t * 96;
#pragma unroll
        for (int i = 0; i < NC4; ++i) {
            float4 v00 = *(const float4*)(p00 + 4 * i);
            float4 v01 = *(const float4*)(p01 + 4 * i);
            float4 v10 = *(const float4*)(p10 + 4 * i);
            float4 v11 = *(const float4*)(p11 + 4 * i);
            float4 wd  = *(const float4*)(wdr + 4 * i);
            float4 v;
            v.x = fmaf(w00, v00.x, fmaf(w01, v01.x, fmaf(w10, v10.x, w11 * v11.x)));
            v.y = fmaf(w00, v00.y, fmaf(w01, v01.y, fmaf(w10, v10.y, w11 * v11.y)));
            v.z = fmaf(w00, v00.z, fmaf(w01, v01.z, fmaf(w10, v10.z, w11 * v11.z)));
            v.w = fmaf(w00, v00.w, fmaf(w01, v01.w, fmaf(w10, v10.w, w11 * v11.w)));
            acc[i].x = fmaf(wd.x, v.x, acc[i].x);
            acc[i].y = fmaf(wd.y, v.y, acc[i].y);
            acc[i].z = fmaf(wd.z, v.z, acc[i].z);
            acc[i].w = fmaf(wd.w, v.w, acc[i].w);
        }
    }

    const int cb = ksel * Cc + c0;
    const float* sbr = ws + OFF_SBR;
    const float* hbr = ws + OFF_HBR;
    float* yb = ybuf + ((size_t)b * C3 + cb) * HWp + p;
#pragma unroll
    for (int i = 0; i < NC4; ++i) {
        float vv[4] = { acc[i].x, acc[i].y, acc[i].z, acc[i].w };
#pragma unroll
        for (int jj = 0; jj < 4; ++jj) {
            int c = cb + 4 * i + jj;
            float v = vv[jj] * sbr[c] + hbr[c];
            yb[(size_t)(4 * i + jj) * HWp] = fmaxf(v, 0.f);
        }
    }
}

__global__ __launch_bounds__(256) void sampdw2_kernel(
    const float* __restrict__ xT, const float* __restrict__ ws, float* __restrict__ ybuf)
{
    const int e = blockIdx.y;
    if (e < 4)       samp_body<3, 24>(e * 24, 0, 0, xT, ws, ybuf);
    else if (e < 12) samp_body<5, 12>((e - 4) * 12, 1, 18, xT, ws, ybuf);
    else             samp_body<7, 8>((e - 12) * 8, 2, 68, xT, ws, ybuf);
}

// Pointwise 288->192 + BN + ReLU
__global__ __launch_bounds__(256) void pwconv_kernel(
    const float* __restrict__ ws_y, const float* __restrict__ ws, float* __restrict__ out)
{
    const float* WPT = ws + OFF_WPT;
    const float* spw = ws + OFF_SPW;
    const float* hpw = ws + OFF_HPW;

    const int tid = threadIdx.x;
    const int p = blockIdx.x * 256 + tid;
    const int o0 = blockIdx.y * 16;
    const int b = blockIdx.z;

    float acc[16];
#pragma unroll
    for (int j = 0; j < 16; ++j) acc[j] = 0.f;

    const float* yb = ws_y + (size_t)b * C3 * HWp + p;
    for (int c = 0; c < C3; ++c) {
        float v = yb[(size_t)c * HWp];
        const float* wrow = WPT + c * Oo + o0;
#pragma unroll
        for (int j = 0; j < 16; ++j) acc[j] += wrow[j] * v;
    }
    float* ob = out + ((size_t)b * Oo + o0) * HWp + p;
#pragma unroll
    for (int j = 0; j < 16; ++j) {
        float v = acc[j] * spw[o0 + j] + hpw[o0 + j];
        ob[(size_t)j * HWp] = fmaxf(v, 0.f);
    }
}

extern "C" void kernel_launch(void* const* d_in, const int* in_sizes, int n_in,
                              void* d_out, int out_size, void* d_ws, size_t ws_size,
                              hipStream_t stream)
{
    const float* x     = (const float*)d_in[0];
    const float* w3    = (const float*)d_in[1];
    const float* b3    = (const float*)d_in[2];
    const float* dw3   = (const float*)d_in[3];
    const float* g3    = (const float*)d_in[4];
    const float* be3   = (const float*)d_in[5];
    const float* m3    = (const float*)d_in[6];
    const float* v3    = (const float*)d_in[7];
    const float* w5    = (const float*)d_in[8];
    const float* b5    = (const float*)d_in[9];
    const float* dw5   = (const float*)d_in[10];
    const float* g5    = (const float*)d_in[11];
    const float* be5   = (const float*)d_in[12];
    const float* m5    = (const float*)d_in[13];
    const float* v5    = (const float*)d_in[14];
    const float* w7    = (const float*)d_in[15];
    const float* b7    = (const float*)d_in[16];
    const float* dw7   = (const float*)d_in[17];
    const float* g7    = (const float*)d_in[18];
    const float* be7   = (const float*)d_in[19];
    const float* m7    = (const float*)d_in[20];
    const float* v7    = (const float*)d_in[21];
    const float* wpw   = (const float*)d_in[22];
    const float* gp    = (const float*)d_in[23];
    const float* bp    = (const float*)d_in[24];
    const float* mp    = (const float*)d_in[25];
    const float* vp    = (const float*)d_in[26];

    float* ws = (float*)d_ws;
    float* out = (float*)d_out;

    {   // 1) prep
        dim3 grid((PREP_N + 255) / 256);
        prep_kernel<<<grid, 256, 0, stream>>>(
            w3, b3, dw3, g3, be3, m3, v3,
            w5, b5, dw5, g5, be5, m5, v5,
            w7, b7, dw7, g7, be7, m7, v7,
            wpw, gp, bp, mp, vp, ws);
    }
    {   // 1b) x NCHW -> NHWC
        dim3 grid(HWp / 256, 6, Bb);
        transpose_kernel<<<grid, 256, 0, stream>>>(x, ws + OFF_XT);
    }
    {   // 2) fused offset conv
        dim3 grid(HWp / 256, COP / 16, Bb);
        offconv_kernel<<<grid, 256, 0, stream>>>(x, ws, ws + OFF_OFF);
    }
    {   // 3) deformable sampling + depthwise + BN + ReLU
        dim3 grid(HWp / 256, 24, Bb);
        sampdw2_kernel<<<grid, 256, 0, stream>>>(ws + OFF_XT, ws, ws + OFF_Y);
    }
    {   // 4) pointwise + BN + ReLU
        dim3 grid(HWp / 256, Oo / 16, Bb);
        pwconv_kernel<<<grid, 256, 0, stream>>>(ws + OFF_Y, ws, out);
    }
}

// Round 3
// 355.715 us; speedup vs baseline: 1.7624x; 1.3499x over previous
//
#include <hip/hip_runtime.h>
#include <math.h>

#define HWp 4096
#define Wd 64
#define Hd 64
#define Cc 96
#define Bb 4
#define COP 176   // padded offset-conv output channels (166 real)
#define Oo 192
#define C3 288

// ---------------- workspace layout (in floats) ----------------
#define OFF_WT    0           // [864][176]
#define OFF_WPT   152064      // [288][192]
#define OFF_WDW   207360      // [96*9|96*25|96*49]
#define OFF_BCAT  215328      // [176]
#define OFF_SBR   215504      // [288]
#define OFF_HBR   215792      // [288]
#define OFF_SPW   216080      // [192]
#define OFF_HPW   216272      // [192]
#define OFF_WDWT  216464      // [3][49][96] transposed dw weights (zero-padded taps)
#define OFF_OFF   230576      // [4][176][4096]
#define OFF_Y     3114160     // [4][288][4096]
#define OFF_XT    7832752     // [4][4096][96] NHWC transposed x
#define PREP_N    230576

__global__ __launch_bounds__(256) void prep_kernel(
    const float* __restrict__ w3, const float* __restrict__ b3, const float* __restrict__ dw3,
    const float* __restrict__ g3, const float* __restrict__ be3, const float* __restrict__ m3, const float* __restrict__ v3,
    const float* __restrict__ w5, const float* __restrict__ b5, const float* __restrict__ dw5,
    const float* __restrict__ g5, const float* __restrict__ be5, const float* __restrict__ m5, const float* __restrict__ v5,
    const float* __restrict__ w7, const float* __restrict__ b7, const float* __restrict__ dw7,
    const float* __restrict__ g7, const float* __restrict__ be7, const float* __restrict__ m7, const float* __restrict__ v7,
    const float* __restrict__ wpw,
    const float* __restrict__ gp, const float* __restrict__ bp, const float* __restrict__ mp, const float* __restrict__ vp,
    float* __restrict__ ws)
{
    int i = blockIdx.x * 256 + threadIdx.x;
    if (i < 152064) {                       // WT [864][176]
        int kidx = i / COP, co = i % COP;
        float v = 0.f;
        if (co < 166) {
            if (co < 18)       v = w3[co * 864 + kidx];
            else if (co < 68)  v = w5[(co - 18) * 864 + kidx];
            else               v = w7[(co - 68) * 864 + kidx];
        }
        ws[OFF_WT + i] = v;
        return;
    }
    int j = i - 152064;
    if (j < 55296) {                        // WPT [288][192]
        int c = j / Oo, o = j % Oo;
        ws[OFF_WPT + j] = wpw[o * C3 + c];
        return;
    }
    j -= 55296;
    if (j < 7968) {                         // wdwf concat
        float v;
        if (j < 864)        v = dw3[j];
        else if (j < 3264)  v = dw5[j - 864];
        else                v = dw7[j - 3264];
        ws[OFF_WDW + j] = v;
        return;
    }
    j -= 7968;
    if (j < COP) {                          // bcat
        float v = 0.f;
        if (j < 18)       v = b3[j];
        else if (j < 68)  v = b5[j - 18];
        else if (j < 166) v = b7[j - 68];
        ws[OFF_BCAT + j] = v;
        return;
    }
    j -= COP;
    if (j < C3) {                           // sbr
        int ks = j / Cc, c = j % Cc;
        const float* g = (ks == 0) ? g3 : (ks == 1) ? g5 : g7;
        const float* v = (ks == 0) ? v3 : (ks == 1) ? v5 : v7;
        ws[OFF_SBR + j] = g[c] / sqrtf(v[c] + 1e-5f);
        return;
    }
    j -= C3;
    if (j < C3) {                           // hbr
        int ks = j / Cc, c = j % Cc;
        const float* g = (ks == 0) ? g3 : (ks == 1) ? g5 : g7;
        const float* v = (ks == 0) ? v3 : (ks == 1) ? v5 : v7;
        const float* be = (ks == 0) ? be3 : (ks == 1) ? be5 : be7;
        const float* m = (ks == 0) ? m3 : (ks == 1) ? m5 : m7;
        float inv = g[c] / sqrtf(v[c] + 1e-5f);
        ws[OFF_HBR + j] = be[c] - m[c] * inv;
        return;
    }
    j -= C3;
    if (j < Oo) {                           // spw
        ws[OFF_SPW + j] = gp[j] / sqrtf(vp[j] + 1e-5f);
        return;
    }
    j -= Oo;
    if (j < Oo) {                           // hpw
        float inv = gp[j] / sqrtf(vp[j] + 1e-5f);
        ws[OFF_HPW + j] = bp[j] - mp[j] * inv;
        return;
    }
    j -= Oo;
    if (j < 14112) {                        // wdwT [3][49][96]
        int ksel = j / 4704, rem = j % 4704;
        int t = rem / 96, c = rem % 96;
        int K2 = (ksel == 0) ? 9 : (ksel == 1) ? 25 : 49;
        const float* dw = (ksel == 0) ? dw3 : (ksel == 1) ? dw5 : dw7;
        ws[OFF_WDWT + j] = (t < K2) ? dw[c * K2 + t] : 0.f;
        return;
    }
}

// NCHW -> NHWC transpose of x into workspace
__global__ __launch_bounds__(256) void transpose_kernel(
    const float* __restrict__ x, float* __restrict__ xT)
{
    const int tid = threadIdx.x;
    const int p = blockIdx.x * 256 + tid;
    const int c0 = blockIdx.y * 16;
    const int b = blockIdx.z;
    float tmp[16];
#pragma unroll
    for (int c = 0; c < 16; ++c)
        tmp[c] = x[((size_t)(b * Cc + c0 + c) << 12) + p];
    float* dst = xT + ((size_t)(b << 12) + p) * 96 + c0;
#pragma unroll
    for (int i = 0; i < 4; ++i) {
        float4 v = make_float4(tmp[4 * i], tmp[4 * i + 1], tmp[4 * i + 2], tmp[4 * i + 3]);
        *(float4*)(dst + 4 * i) = v;
    }
}

// Fused 3x offset conv as one implicit GEMM
__global__ __launch_bounds__(256) void offconv_kernel(
    const float* __restrict__ x, const float* __restrict__ ws, float* __restrict__ off)
{
    const float* WT = ws + OFF_WT;
    const float* bcat = ws + OFF_BCAT;
    const int tid = threadIdx.x;
    const int p = blockIdx.x * 256 + tid;
    const int h = p >> 6, w = p & 63;
    const int co0 = blockIdx.y * 16;
    const int b = blockIdx.z;

    float acc[16];
#pragma unroll
    for (int j = 0; j < 16; ++j) acc[j] = bcat[co0 + j];

    const float* xb = x + (size_t)b * Cc * HWp;
    for (int c = 0; c < Cc; ++c) {
        const float* xc = xb + c * HWp;
        const float* wr = WT + (c * 9) * COP + co0;
#pragma unroll
        for (int ky = 0; ky < 3; ++ky) {
            int yy = h + ky - 1;
            bool rok = ((unsigned)yy < 64u);
            int ycl = min(max(yy, 0), 63);
#pragma unroll
            for (int kx = 0; kx < 3; ++kx) {
                int xx = w + kx - 1;
                bool ok = rok && ((unsigned)xx < 64u);
                int xcl = min(max(xx, 0), 63);
                float v = xc[(ycl << 6) + xcl];
                v = ok ? v : 0.f;
                const float* wrow = wr + (ky * 3 + kx) * COP;
#pragma unroll
                for (int j = 0; j < 16; ++j) acc[j] += wrow[j] * v;
            }
        }
    }
    float* ob = off + ((size_t)b * COP + co0) * HWp + p;
#pragma unroll
    for (int j = 0; j < 16; ++j) ob[(size_t)j * HWp] = acc[j];
}

// ---- Deformable sampling v3: channel-in-lane NHWC gather ----
// thread: c4 = tid%24 (4 channels as float4), q = tid/24 (10 positions/block)
template<int K>
__device__ __forceinline__ void samp_v3(
    int ksel, int tb,
    const float* __restrict__ xT, const float* __restrict__ ws, float* __restrict__ ybuf)
{
    constexpr int K2 = K * K;
    constexpr int R = (K - 1) / 2;
    __shared__ float soff[2 * 49 * 10];

    const int tid = threadIdx.x;
    const int b = blockIdx.z;
    const int p0 = blockIdx.x * 10;

    // cooperative prefetch of this block's offsets into LDS
    const float* offbase = ws + OFF_OFF + ((size_t)b * COP + tb) * HWp;
    for (int i = tid; i < 2 * K2 * 10; i += 256) {
        int t = i / 10, q = i % 10;
        int pp = min(p0 + q, 4095);
        soff[i] = offbase[(size_t)t * HWp + pp];
    }
    __syncthreads();

    if (tid >= 240) return;
    const int c4 = tid % 24;
    const int q  = tid / 24;
    const int p  = p0 + q;
    if (p >= 4096) return;
    const int hh = p >> 6, wp = p & 63;
    const int c = 4 * c4;

    const float* xb  = xT + (((size_t)b) << 12) * 96;
    const float* wdT = ws + OFF_WDWT + ksel * 4704 + c;

    float4 acc = make_float4(0.f, 0.f, 0.f, 0.f);

#pragma unroll 2
    for (int t = 0; t < K2; ++t) {
        const int ky = t / K - R;
        const int kx = t % K - R;
        float dy = soff[t * 10 + q];
        float dx = soff[(K2 + t) * 10 + q];
        float py = fminf(fmaxf((float)(hh + ky) + dy, 0.f), 63.f);
        float px = fminf(fmaxf((float)(wp + kx) + dx, 0.f), 63.f);
        float fy = floorf(py), fx = floorf(px);
        int y0 = (int)fy, x0 = (int)fx;
        float wy = py - fy, wx = px - fx;
        int y1 = min(y0 + 1, 63), x1 = min(x0 + 1, 63);
        float w11 = wy * wx;
        float w10 = wy - w11;
        float w01 = wx - w11;
        float w00 = 1.f - wy - wx + w11;
        const float4 v00 = *(const float4*)(xb + (size_t)((y0 << 6) + x0) * 96 + c);
        const float4 v01 = *(const float4*)(xb + (size_t)((y0 << 6) + x1) * 96 + c);
        const float4 v10 = *(const float4*)(xb + (size_t)((y1 << 6) + x0) * 96 + c);
        const float4 v11 = *(const float4*)(xb + (size_t)((y1 << 6) + x1) * 96 + c);
        const float4 wd  = *(const float4*)(wdT + t * 96);
        float4 v;
        v.x = fmaf(w00, v00.x, fmaf(w01, v01.x, fmaf(w10, v10.x, w11 * v11.x)));
        v.y = fmaf(w00, v00.y, fmaf(w01, v01.y, fmaf(w10, v10.y, w11 * v11.y)));
        v.z = fmaf(w00, v00.z, fmaf(w01, v01.z, fmaf(w10, v10.z, w11 * v11.z)));
        v.w = fmaf(w00, v00.w, fmaf(w01, v01.w, fmaf(w10, v10.w, w11 * v11.w)));
        acc.x = fmaf(wd.x, v.x, acc.x);
        acc.y = fmaf(wd.y, v.y, acc.y);
        acc.z = fmaf(wd.z, v.z, acc.z);
        acc.w = fmaf(wd.w, v.w, acc.w);
    }

    const int cb = ksel * Cc + c;
    const float4 s4 = *(const float4*)(ws + OFF_SBR + cb);
    const float4 h4 = *(const float4*)(ws + OFF_HBR + cb);
    float* yb = ybuf + ((size_t)b * C3 + cb) * HWp + p;
    yb[0]           = fmaxf(fmaf(acc.x, s4.x, h4.x), 0.f);
    yb[HWp]         = fmaxf(fmaf(acc.y, s4.y, h4.y), 0.f);
    yb[2 * (size_t)HWp] = fmaxf(fmaf(acc.z, s4.z, h4.z), 0.f);
    yb[3 * (size_t)HWp] = fmaxf(fmaf(acc.w, s4.w, h4.w), 0.f);
}

__global__ __launch_bounds__(256) void sampdw3_kernel(
    const float* __restrict__ xT, const float* __restrict__ ws, float* __restrict__ ybuf)
{
    const int e = blockIdx.y;
    if (e == 0)      samp_v3<3>(0, 0,  xT, ws, ybuf);
    else if (e == 1) samp_v3<5>(1, 18, xT, ws, ybuf);
    else             samp_v3<7>(2, 68, xT, ws, ybuf);
}

// Pointwise 288->192 + BN + ReLU
__global__ __launch_bounds__(256) void pwconv_kernel(
    const float* __restrict__ ws_y, const float* __restrict__ ws, float* __restrict__ out)
{
    const float* WPT = ws + OFF_WPT;
    const float* spw = ws + OFF_SPW;
    const float* hpw = ws + OFF_HPW;

    const int tid = threadIdx.x;
    const int p = blockIdx.x * 256 + tid;
    const int o0 = blockIdx.y * 16;
    const int b = blockIdx.z;

    float acc[16];
#pragma unroll
    for (int j = 0; j < 16; ++j) acc[j] = 0.f;

    const float* yb = ws_y + (size_t)b * C3 * HWp + p;
    for (int c = 0; c < C3; ++c) {
        float v = yb[(size_t)c * HWp];
        const float* wrow = WPT + c * Oo + o0;
#pragma unroll
        for (int j = 0; j < 16; ++j) acc[j] += wrow[j] * v;
    }
    float* ob = out + ((size_t)b * Oo + o0) * HWp + p;
#pragma unroll
    for (int j = 0; j < 16; ++j) {
        float v = acc[j] * spw[o0 + j] + hpw[o0 + j];
        ob[(size_t)j * HWp] = fmaxf(v, 0.f);
    }
}

extern "C" void kernel_launch(void* const* d_in, const int* in_sizes, int n_in,
                              void* d_out, int out_size, void* d_ws, size_t ws_size,
                              hipStream_t stream)
{
    const float* x     = (const float*)d_in[0];
    const float* w3    = (const float*)d_in[1];
    const float* b3    = (const float*)d_in[2];
    const float* dw3   = (const float*)d_in[3];
    const float* g3    = (const float*)d_in[4];
    const float* be3   = (const float*)d_in[5];
    const float* m3    = (const float*)d_in[6];
    const float* v3    = (const float*)d_in[7];
    const float* w5    = (const float*)d_in[8];
    const float* b5    = (const float*)d_in[9];
    const float* dw5   = (const float*)d_in[10];
    const float* g5    = (const float*)d_in[11];
    const float* be5   = (const float*)d_in[12];
    const float* m5    = (const float*)d_in[13];
    const float* v5    = (const float*)d_in[14];
    const float* w7    = (const float*)d_in[15];
    const float* b7    = (const float*)d_in[16];
    const float* dw7   = (const float*)d_in[17];
    const float* g7    = (const float*)d_in[18];
    const float* be7   = (const float*)d_in[19];
    const float* m7    = (const float*)d_in[20];
    const float* v7    = (const float*)d_in[21];
    const float* wpw   = (const float*)d_in[22];
    const float* gp    = (const float*)d_in[23];
    const float* bp    = (const float*)d_in[24];
    const float* mp    = (const float*)d_in[25];
    const float* vp    = (const float*)d_in[26];

    float* ws = (float*)d_ws;
    float* out = (float*)d_out;

    {   // 1) prep
        dim3 grid((PREP_N + 255) / 256);
        prep_kernel<<<grid, 256, 0, stream>>>(
            w3, b3, dw3, g3, be3, m3, v3,
            w5, b5, dw5, g5, be5, m5, v5,
            w7, b7, dw7, g7, be7, m7, v7,
            wpw, gp, bp, mp, vp, ws);
    }
    {   // 1b) x NCHW -> NHWC
        dim3 grid(HWp / 256, 6, Bb);
        transpose_kernel<<<grid, 256, 0, stream>>>(x, ws + OFF_XT);
    }
    {   // 2) fused offset conv
        dim3 grid(HWp / 256, COP / 16, Bb);
        offconv_kernel<<<grid, 256, 0, stream>>>(x, ws, ws + OFF_OFF);
    }
    {   // 3) deformable sampling + depthwise + BN + ReLU (channel-in-lane)
        dim3 grid(410, 3, Bb);
        sampdw3_kernel<<<grid, 256, 0, stream>>>(ws + OFF_XT, ws, ws + OFF_Y);
    }
    {   // 4) pointwise + BN + ReLU
        dim3 grid(HWp / 256, Oo / 16, Bb);
        pwconv_kernel<<<grid, 256, 0, stream>>>(ws + OFF_Y, ws, out);
    }
}

// Round 4
// 329.286 us; speedup vs baseline: 1.9039x; 1.0803x over previous
//
#include <hip/hip_runtime.h>
#include <math.h>

typedef unsigned short u16;
typedef short s16x8 __attribute__((ext_vector_type(8)));
typedef float f32x4 __attribute__((ext_vector_type(4)));

#define HWp 4096
#define Cc 96
#define Bb 4
#define COP 176
#define Oo 192
#define C3 288

// ---------- fp32 workspace region (float offsets) ----------
#define OFF_OFF   0           // [4][176][4096]
#define OFF_WDWT  2883584     // [3][49][96]
#define OFF_BCAT  2897696     // [176]
#define OFF_SBR   2897872     // [288]
#define OFF_HBR   2898160     // [288]
#define OFF_SPW   2898448     // [192]
#define OFF_HPW   2898640     // [192]
#define FP32_END  2898832
// ---------- bf16 region (u16 offsets, base = ws + FP32_END) ----------
#define BF_XTPAD  0           // [4][66][66][96]
#define BF_WOF    1672704     // 11 frag x 27 step x 64 lane x 8
#define BF_WPW    1824768     // 12 frag x 9 step x 64 lane x 8
#define BF_YT     1880064     // [4][4096][288]

__device__ __forceinline__ u16 f2bf(float f) {
    union { float f; unsigned u; } t; t.f = f;
    unsigned u = t.u;
    return (u16)((u + 0x7fffu + ((u >> 16) & 1u)) >> 16);
}
__device__ __forceinline__ float bflo(unsigned u) { return __uint_as_float(u << 16); }
__device__ __forceinline__ float bfhi(unsigned u) { return __uint_as_float(u & 0xffff0000u); }

// ---------------- prep: repack weights, fold BN ----------------
__global__ __launch_bounds__(256) void prep_kernel(
    const float* __restrict__ w3, const float* __restrict__ b3, const float* __restrict__ dw3,
    const float* __restrict__ g3, const float* __restrict__ be3, const float* __restrict__ m3, const float* __restrict__ v3,
    const float* __restrict__ w5, const float* __restrict__ b5, const float* __restrict__ dw5,
    const float* __restrict__ g5, const float* __restrict__ be5, const float* __restrict__ m5, const float* __restrict__ v5,
    const float* __restrict__ w7, const float* __restrict__ b7, const float* __restrict__ dw7,
    const float* __restrict__ g7, const float* __restrict__ be7, const float* __restrict__ m7, const float* __restrict__ v7,
    const float* __restrict__ wpw,
    const float* __restrict__ gp, const float* __restrict__ bp, const float* __restrict__ mp, const float* __restrict__ vp,
    float* __restrict__ ws)
{
    u16* bf = (u16*)(ws + FP32_END);
    int i = blockIdx.x * 256 + threadIdx.x;
    if (i < 152064) {                       // WOF frag-linear bf16
        int f = i / 13824, r = i % 13824;
        int s = r >> 9, l = r & 511;
        int lane = l >> 3, j = l & 7;
        int o = f * 16 + (lane & 15);
        int k = s * 32 + (lane >> 4) * 8 + j;   // k = tap*96 + c
        int tap = k / 96, c = k % 96;
        float v = 0.f;
        if (o < 166) {
            if (o < 18)       v = w3[o * 864 + c * 9 + tap];
            else if (o < 68)  v = w5[(o - 18) * 864 + c * 9 + tap];
            else              v = w7[(o - 68) * 864 + c * 9 + tap];
        }
        bf[BF_WOF + i] = f2bf(v);
        return;
    }
    int j = i - 152064;
    if (j < 55296) {                        // WPW frag-linear bf16
        int f = j / 4608, r = j % 4608;
        int s = r >> 9, l = r & 511;
        int lane = l >> 3, jj = l & 7;
        int o = f * 16 + (lane & 15);
        int k = s * 32 + (lane >> 4) * 8 + jj;
        bf[BF_WPW + j] = f2bf(wpw[o * C3 + k]);
        return;
    }
    j -= 55296;
    if (j < 14112) {                        // wdwT [3][49][96] fp32
        int ksel = j / 4704, rem = j % 4704;
        int t = rem / 96, c = rem % 96;
        int K2 = (ksel == 0) ? 9 : (ksel == 1) ? 25 : 49;
        const float* dw = (ksel == 0) ? dw3 : (ksel == 1) ? dw5 : dw7;
        ws[OFF_WDWT + j] = (t < K2) ? dw[c * K2 + t] : 0.f;
        return;
    }
    j -= 14112;
    if (j < COP) {                          // bcat
        float v = 0.f;
        if (j < 18)       v = b3[j];
        else if (j < 68)  v = b5[j - 18];
        else if (j < 166) v = b7[j - 68];
        ws[OFF_BCAT + j] = v;
        return;
    }
    j -= COP;
    if (j < C3) {                           // sbr
        int ks = j / Cc, c = j % Cc;
        const float* g = (ks == 0) ? g3 : (ks == 1) ? g5 : g7;
        const float* v = (ks == 0) ? v3 : (ks == 1) ? v5 : v7;
        ws[OFF_SBR + j] = g[c] / sqrtf(v[c] + 1e-5f);
        return;
    }
    j -= C3;
    if (j < C3) {                           // hbr
        int ks = j / Cc, c = j % Cc;
        const float* g = (ks == 0) ? g3 : (ks == 1) ? g5 : g7;
        const float* v = (ks == 0) ? v3 : (ks == 1) ? v5 : v7;
        const float* be = (ks == 0) ? be3 : (ks == 1) ? be5 : be7;
        const float* m = (ks == 0) ? m3 : (ks == 1) ? m5 : m7;
        float inv = g[c] / sqrtf(v[c] + 1e-5f);
        ws[OFF_HBR + j] = be[c] - m[c] * inv;
        return;
    }
    j -= C3;
    if (j < Oo) { ws[OFF_SPW + j] = gp[j] / sqrtf(vp[j] + 1e-5f); return; }
    j -= Oo;
    if (j < Oo) {
        float inv = gp[j] / sqrtf(vp[j] + 1e-5f);
        ws[OFF_HPW + j] = bp[j] - mp[j] * inv;
        return;
    }
}

// ---------------- xTpad builder: NCHW fp32 -> padded NHWC bf16 ----------------
__global__ __launch_bounds__(256) void xtpad_kernel(
    const float* __restrict__ x, float* __restrict__ ws)
{
    u16* bf = (u16*)(ws + FP32_END);
    int i = blockIdx.x * 256 + threadIdx.x;
    if (i >= 4 * 66 * 66 * 24) return;
    int c4 = i % 24, rem = i / 24;
    int col = rem % 66, rem2 = rem / 66;
    int row = rem2 % 66, b = rem2 / 66;
    int h = row - 1, w = col - 1;
    unsigned lo = 0, hi = 0;
    if ((unsigned)h < 64u && (unsigned)w < 64u) {
        const float* xp = x + (((size_t)(b * Cc + c4 * 4)) << 12) + (h << 6) + w;
        u16 a0 = f2bf(xp[0]);
        u16 a1 = f2bf(xp[HWp]);
        u16 a2 = f2bf(xp[2 * HWp]);
        u16 a3 = f2bf(xp[3 * HWp]);
        lo = (unsigned)a0 | ((unsigned)a1 << 16);
        hi = (unsigned)a2 | ((unsigned)a3 << 16);
    }
    u16* dst = bf + BF_XTPAD + ((size_t)(b * 66 + row) * 66 + col) * 96 + c4 * 4;
    *(uint2*)dst = make_uint2(lo, hi);
}

// ---------------- offset conv: bf16 MFMA GEMM D[176][pos] ----------------
// wave = 11 m-frags (all 176 co) x 2 n-frags (32 positions), K = 864 (27 steps)
__global__ __launch_bounds__(128) void offconv_mfma(
    const float* __restrict__ ws, float* __restrict__ off)
{
    const u16* bf = (const u16*)(ws + FP32_END);
    const u16* xp = bf + BF_XTPAD;
    const u16* wof = bf + BF_WOF;
    const int lane = threadIdx.x & 63, wid = threadIdx.x >> 6;
    const int b = blockIdx.z;
    const int p0 = blockIdx.x * 64 + wid * 32;
    const int h = p0 >> 6, w0 = p0 & 63;
    const int lane15 = lane & 15, quad = lane >> 4;

    f32x4 acc[11][2];
#pragma unroll
    for (int f = 0; f < 11; ++f) {
        acc[f][0] = (f32x4){0.f, 0.f, 0.f, 0.f};
        acc[f][1] = (f32x4){0.f, 0.f, 0.f, 0.f};
    }

    const u16* bbase = xp + ((size_t)(b * 66 + h + 1) * 66 + (w0 + 1 + lane15)) * 96 + quad * 8;

    for (int tap = 0; tap < 9; ++tap) {
        int tq = tap / 3;
        int drow = (tq - 1) * 66 + (tap - 3 * tq - 1);   // ky*66 + kx
        const u16* bt = bbase + drow * 96;
#pragma unroll
        for (int cc = 0; cc < 3; ++cc) {
            const int s = tap * 3 + cc;
            s16x8 b0 = *(const s16x8*)(bt + cc * 32);
            s16x8 b1 = *(const s16x8*)(bt + cc * 32 + 16 * 96);
#pragma unroll
            for (int f = 0; f < 11; ++f) {
                s16x8 a = *(const s16x8*)(wof + ((size_t)(f * 27 + s) * 64 + lane) * 8);
                acc[f][0] = __builtin_amdgcn_mfma_f32_16x16x32_bf16(a, b0, acc[f][0], 0, 0, 0);
                acc[f][1] = __builtin_amdgcn_mfma_f32_16x16x32_bf16(a, b1, acc[f][1], 0, 0, 0);
            }
        }
    }

    const float* bcat = ws + OFF_BCAT;
#pragma unroll
    for (int f = 0; f < 11; ++f) {
#pragma unroll
        for (int nf = 0; nf < 2; ++nf) {
            int p = p0 + nf * 16 + lane15;
            float* dst = off + (((size_t)(b * COP + f * 16 + quad * 4)) << 12) + p;
#pragma unroll
            for (int r = 0; r < 4; ++r)
                dst[(size_t)r << 12] = acc[f][nf][r] + bcat[f * 16 + quad * 4 + r];
        }
    }
}

// ---------------- deformable sampling v4: bf16 NHWC gather, bf16 NHWC y ----------------
template<int K>
__device__ __forceinline__ void samp_v4(
    int ksel, int tb, const float* __restrict__ ws, u16* __restrict__ yt)
{
    constexpr int K2 = K * K;
    constexpr int R = (K - 1) / 2;
    __shared__ float soff[2 * 49 * 10];

    const int tid = threadIdx.x;
    const int b = blockIdx.z;
    const int p0 = blockIdx.x * 10;

    const float* offbase = ws + OFF_OFF + ((size_t)(b * COP + tb)) * HWp;
    for (int i = tid; i < 2 * K2 * 10; i += 256) {
        int t = i / 10, q = i % 10;
        int pp = min(p0 + q, 4095);
        soff[i] = offbase[(size_t)t * HWp + pp];
    }
    __syncthreads();

    if (tid >= 240) return;
    const int c4 = tid % 24;
    const int q  = tid / 24;
    const int p  = p0 + q;
    if (p >= 4096) return;
    const int hh = p >> 6, wp = p & 63;
    const int c = 4 * c4;

    const u16* xb = (const u16*)(ws + FP32_END) + BF_XTPAD + (size_t)b * 66 * 66 * 96;
    const float* wdT = ws + OFF_WDWT + ksel * 4704 + c;

    float4 acc = make_float4(0.f, 0.f, 0.f, 0.f);

#pragma unroll 2
    for (int t = 0; t < K2; ++t) {
        const int ky = t / K - R;
        const int kx = t % K - R;
        float dy = soff[t * 10 + q];
        float dx = soff[(K2 + t) * 10 + q];
        float py = fminf(fmaxf((float)(hh + ky) + dy, 0.f), 63.f);
        float px = fminf(fmaxf((float)(wp + kx) + dx, 0.f), 63.f);
        float fy = floorf(py), fx = floorf(px);
        int y0 = (int)fy, x0 = (int)fx;
        float wy = py - fy, wx = px - fx;
        int y1 = min(y0 + 1, 63), x1 = min(x0 + 1, 63);
        float w11 = wy * wx;
        float w10 = wy - w11;
        float w01 = wx - w11;
        float w00 = 1.f - wy - wx + w11;
        const uint2 u00 = *(const uint2*)(xb + ((size_t)((y0 + 1) * 66 + (x0 + 1))) * 96 + c);
        const uint2 u01 = *(const uint2*)(xb + ((size_t)((y0 + 1) * 66 + (x1 + 1))) * 96 + c);
        const uint2 u10 = *(const uint2*)(xb + ((size_t)((y1 + 1) * 66 + (x0 + 1))) * 96 + c);
        const uint2 u11 = *(const uint2*)(xb + ((size_t)((y1 + 1) * 66 + (x1 + 1))) * 96 + c);
        const float4 wd = *(const float4*)(wdT + t * 96);
        float v0 = fmaf(w00, bflo(u00.x), fmaf(w01, bflo(u01.x), fmaf(w10, bflo(u10.x), w11 * bflo(u11.x))));
        float v1 = fmaf(w00, bfhi(u00.x), fmaf(w01, bfhi(u01.x), fmaf(w10, bfhi(u10.x), w11 * bfhi(u11.x))));
        float v2 = fmaf(w00, bflo(u00.y), fmaf(w01, bflo(u01.y), fmaf(w10, bflo(u10.y), w11 * bflo(u11.y))));
        float v3 = fmaf(w00, bfhi(u00.y), fmaf(w01, bfhi(u01.y), fmaf(w10, bfhi(u10.y), w11 * bfhi(u11.y))));
        acc.x = fmaf(wd.x, v0, acc.x);
        acc.y = fmaf(wd.y, v1, acc.y);
        acc.z = fmaf(wd.z, v2, acc.z);
        acc.w = fmaf(wd.w, v3, acc.w);
    }

    const int cb = ksel * Cc + c;
    const float4 s4 = *(const float4*)(ws + OFF_SBR + cb);
    const float4 h4 = *(const float4*)(ws + OFF_HBR + cb);
    u16 r0 = f2bf(fmaxf(fmaf(acc.x, s4.x, h4.x), 0.f));
    u16 r1 = f2bf(fmaxf(fmaf(acc.y, s4.y, h4.y), 0.f));
    u16 r2 = f2bf(fmaxf(fmaf(acc.z, s4.z, h4.z), 0.f));
    u16 r3 = f2bf(fmaxf(fmaf(acc.w, s4.w, h4.w), 0.f));
    u16* dst = yt + ((size_t)(b << 12) + p) * C3 + cb;
    *(uint2*)dst = make_uint2((unsigned)r0 | ((unsigned)r1 << 16),
                              (unsigned)r2 | ((unsigned)r3 << 16));
}

__global__ __launch_bounds__(256) void sampdw4_kernel(float* __restrict__ ws)
{
    u16* yt = (u16*)(ws + FP32_END) + BF_YT;
    const int e = blockIdx.y;
    if (e == 0)      samp_v4<3>(0, 0,  ws, yt);
    else if (e == 1) samp_v4<5>(1, 18, ws, yt);
    else             samp_v4<7>(2, 68, ws, yt);
}

// ---------------- pointwise: bf16 MFMA GEMM D[192][pos] + BN + ReLU ----------------
// wave = 12 m-frags x 2 n-frags (32 positions), K = 288 (9 steps)
__global__ __launch_bounds__(128) void pwconv_mfma(
    const float* __restrict__ ws, float* __restrict__ out)
{
    const u16* bf = (const u16*)(ws + FP32_END);
    const u16* yt = bf + BF_YT;
    const u16* wpw = bf + BF_WPW;
    const int lane = threadIdx.x & 63, wid = threadIdx.x >> 6;
    const int b = blockIdx.z;
    const int p0 = blockIdx.x * 64 + wid * 32;
    const int lane15 = lane & 15, quad = lane >> 4;

    f32x4 acc[12][2];
#pragma unroll
    for (int f = 0; f < 12; ++f) {
        acc[f][0] = (f32x4){0.f, 0.f, 0.f, 0.f};
        acc[f][1] = (f32x4){0.f, 0.f, 0.f, 0.f};
    }

    const u16* bbase = yt + ((size_t)(b << 12) + p0 + lane15) * C3 + quad * 8;

#pragma unroll
    for (int s = 0; s < 9; ++s) {
        s16x8 b0 = *(const s16x8*)(bbase + s * 32);
        s16x8 b1 = *(const s16x8*)(bbase + 16 * C3 + s * 32);
#pragma unroll
        for (int f = 0; f < 12; ++f) {
            s16x8 a = *(const s16x8*)(wpw + ((size_t)(f * 9 + s) * 64 + lane) * 8);
            acc[f][0] = __builtin_amdgcn_mfma_f32_16x16x32_bf16(a, b0, acc[f][0], 0, 0, 0);
            acc[f][1] = __builtin_amdgcn_mfma_f32_16x16x32_bf16(a, b1, acc[f][1], 0, 0, 0);
        }
    }

    const float* spw = ws + OFF_SPW;
    const float* hpw = ws + OFF_HPW;
#pragma unroll
    for (int f = 0; f < 12; ++f) {
#pragma unroll
        for (int nf = 0; nf < 2; ++nf) {
            int p = p0 + nf * 16 + lane15;
            float* dst = out + (((size_t)(b * Oo + f * 16 + quad * 4)) << 12) + p;
#pragma unroll
            for (int r = 0; r < 4; ++r) {
                int o = f * 16 + quad * 4 + r;
                dst[(size_t)r << 12] = fmaxf(fmaf(acc[f][nf][r], spw[o], hpw[o]), 0.f);
            }
        }
    }
}

extern "C" void kernel_launch(void* const* d_in, const int* in_sizes, int n_in,
                              void* d_out, int out_size, void* d_ws, size_t ws_size,
                              hipStream_t stream)
{
    const float* x     = (const float*)d_in[0];
    const float* w3    = (const float*)d_in[1];
    const float* b3    = (const float*)d_in[2];
    const float* dw3   = (const float*)d_in[3];
    const float* g3    = (const float*)d_in[4];
    const float* be3   = (const float*)d_in[5];
    const float* m3    = (const float*)d_in[6];
    const float* v3    = (const float*)d_in[7];
    const float* w5    = (const float*)d_in[8];
    const float* b5    = (const float*)d_in[9];
    const float* dw5   = (const float*)d_in[10];
    const float* g5    = (const float*)d_in[11];
    const float* be5   = (const float*)d_in[12];
    const float* m5    = (const float*)d_in[13];
    const float* v5    = (const float*)d_in[14];
    const float* w7    = (const float*)d_in[15];
    const float* b7    = (const float*)d_in[16];
    const float* dw7   = (const float*)d_in[17];
    const float* g7    = (const float*)d_in[18];
    const float* be7   = (const float*)d_in[19];
    const float* m7    = (const float*)d_in[20];
    const float* v7    = (const float*)d_in[21];
    const float* wpw   = (const float*)d_in[22];
    const float* gp    = (const float*)d_in[23];
    const float* bp    = (const float*)d_in[24];
    const float* mp    = (const float*)d_in[25];
    const float* vp    = (const float*)d_in[26];

    float* ws = (float*)d_ws;
    float* out = (float*)d_out;

    {   // 1) prep: repack weights (frag-linear bf16), fold BN
        prep_kernel<<<870, 256, 0, stream>>>(
            w3, b3, dw3, g3, be3, m3, v3,
            w5, b5, dw5, g5, be5, m5, v5,
            w7, b7, dw7, g7, be7, m7, v7,
            wpw, gp, bp, mp, vp, ws);
    }
    {   // 1b) x -> padded NHWC bf16
        xtpad_kernel<<<1634, 256, 0, stream>>>(x, ws);
    }
    {   // 2) fused offset conv (MFMA)
        dim3 grid(64, 1, Bb);
        offconv_mfma<<<grid, 128, 0, stream>>>(ws, ws + OFF_OFF);
    }
    {   // 3) deformable sampling + depthwise + BN + ReLU
        dim3 grid(410, 3, Bb);
        sampdw4_kernel<<<grid, 256, 0, stream>>>(ws);
    }
    {   // 4) pointwise (MFMA) + BN + ReLU
        dim3 grid(64, 1, Bb);
        pwconv_mfma<<<grid, 128, 0, stream>>>(ws, out);
    }
}

// Round 5
// 264.614 us; speedup vs baseline: 2.3692x; 1.2444x over previous
//
#include <hip/hip_runtime.h>
#include <math.h>

typedef unsigned short u16;
typedef short s16x8 __attribute__((ext_vector_type(8)));
typedef float f32x4 __attribute__((ext_vector_type(4)));

#define HWp 4096
#define Cc 96
#define Bb 4
#define Oo 192
#define C3 288

// ---------- fp32 workspace region (float offsets) ----------
#define OFF_OFF   0           // [4][192][4096] (rows 176..191 scratch)
#define OFF_WDWT  3145728     // [3][49][96]
#define OFF_BCAT  3159840     // [192] (166.. zero)
#define OFF_SBR   3160032     // [288]
#define OFF_HBR   3160320     // [288]
#define OFF_SPW   3160608     // [192]
#define OFF_HPW   3160800     // [192]
#define FP32_END  3160992
// ---------- bf16 region (u16 offsets, base = ws + FP32_END) ----------
#define BF_XTPAD  0           // [4][66][66][96]
#define BF_WOF    1672704     // 12 frag x 27 step x 64 lane x 8
#define BF_WPW    1838592     // 12 frag x 9 step x 64 lane x 8
#define BF_YT     1893888     // [4][4096][288]

__device__ __forceinline__ u16 f2bf(float f) {
    union { float f; unsigned u; } t; t.f = f;
    unsigned u = t.u;
    return (u16)((u + 0x7fffu + ((u >> 16) & 1u)) >> 16);
}
__device__ __forceinline__ float bflo(unsigned u) { return __uint_as_float(u << 16); }
__device__ __forceinline__ float bfhi(unsigned u) { return __uint_as_float(u & 0xffff0000u); }

// ---------------- prep: repack weights, fold BN ----------------
__global__ __launch_bounds__(256) void prep_kernel(
    const float* __restrict__ w3, const float* __restrict__ b3, const float* __restrict__ dw3,
    const float* __restrict__ g3, const float* __restrict__ be3, const float* __restrict__ m3, const float* __restrict__ v3,
    const float* __restrict__ w5, const float* __restrict__ b5, const float* __restrict__ dw5,
    const float* __restrict__ g5, const float* __restrict__ be5, const float* __restrict__ m5, const float* __restrict__ v5,
    const float* __restrict__ w7, const float* __restrict__ b7, const float* __restrict__ dw7,
    const float* __restrict__ g7, const float* __restrict__ be7, const float* __restrict__ m7, const float* __restrict__ v7,
    const float* __restrict__ wpw,
    const float* __restrict__ gp, const float* __restrict__ bp, const float* __restrict__ mp, const float* __restrict__ vp,
    float* __restrict__ ws)
{
    u16* bf = (u16*)(ws + FP32_END);
    int i = blockIdx.x * 256 + threadIdx.x;
    if (i < 165888) {                       // WOF frag-linear bf16, 12 m-frags
        int f = i / 13824, r = i % 13824;
        int s = r >> 9, l = r & 511;
        int lane = l >> 3, j = l & 7;
        int o = f * 16 + (lane & 15);
        int k = s * 32 + (lane >> 4) * 8 + j;   // k = tap*96 + c
        int tap = k / 96, c = k % 96;
        float v = 0.f;
        if (o < 18)       v = w3[o * 864 + c * 9 + tap];
        else if (o < 68)  v = w5[(o - 18) * 864 + c * 9 + tap];
        else if (o < 166) v = w7[(o - 68) * 864 + c * 9 + tap];
        bf[BF_WOF + i] = f2bf(v);
        return;
    }
    int j = i - 165888;
    if (j < 55296) {                        // WPW frag-linear bf16
        int f = j / 4608, r = j % 4608;
        int s = r >> 9, l = r & 511;
        int lane = l >> 3, jj = l & 7;
        int o = f * 16 + (lane & 15);
        int k = s * 32 + (lane >> 4) * 8 + jj;
        bf[BF_WPW + j] = f2bf(wpw[o * C3 + k]);
        return;
    }
    j -= 55296;
    if (j < 14112) {                        // wdwT [3][49][96] fp32
        int ksel = j / 4704, rem = j % 4704;
        int t = rem / 96, c = rem % 96;
        int K2 = (ksel == 0) ? 9 : (ksel == 1) ? 25 : 49;
        const float* dw = (ksel == 0) ? dw3 : (ksel == 1) ? dw5 : dw7;
        ws[OFF_WDWT + j] = (t < K2) ? dw[c * K2 + t] : 0.f;
        return;
    }
    j -= 14112;
    if (j < 192) {                          // bcat (padded)
        float v = 0.f;
        if (j < 18)       v = b3[j];
        else if (j < 68)  v = b5[j - 18];
        else if (j < 166) v = b7[j - 68];
        ws[OFF_BCAT + j] = v;
        return;
    }
    j -= 192;
    if (j < C3) {                           // sbr
        int ks = j / Cc, c = j % Cc;
        const float* g = (ks == 0) ? g3 : (ks == 1) ? g5 : g7;
        const float* v = (ks == 0) ? v3 : (ks == 1) ? v5 : v7;
        ws[OFF_SBR + j] = g[c] / sqrtf(v[c] + 1e-5f);
        return;
    }
    j -= C3;
    if (j < C3) {                           // hbr
        int ks = j / Cc, c = j % Cc;
        const float* g = (ks == 0) ? g3 : (ks == 1) ? g5 : g7;
        const float* v = (ks == 0) ? v3 : (ks == 1) ? v5 : v7;
        const float* be = (ks == 0) ? be3 : (ks == 1) ? be5 : be7;
        const float* m = (ks == 0) ? m3 : (ks == 1) ? m5 : m7;
        float inv = g[c] / sqrtf(v[c] + 1e-5f);
        ws[OFF_HBR + j] = be[c] - m[c] * inv;
        return;
    }
    j -= C3;
    if (j < Oo) { ws[OFF_SPW + j] = gp[j] / sqrtf(vp[j] + 1e-5f); return; }
    j -= Oo;
    if (j < Oo) {
        float inv = gp[j] / sqrtf(vp[j] + 1e-5f);
        ws[OFF_HPW + j] = bp[j] - mp[j] * inv;
        return;
    }
}
#define PREP_N (165888 + 55296 + 14112 + 192 + 288 + 288 + 192 + 192)

// ---------------- xTpad interior: coalesced LDS transpose ----------------
__global__ __launch_bounds__(256) void xtpad_kernel(
    const float* __restrict__ x, float* __restrict__ ws)
{
    __shared__ u16 sT[64 * 104];
    u16* bfm = (u16*)(ws + FP32_END);
    const int tid = threadIdx.x;
    const int h = blockIdx.x, b = blockIdx.y;
    const float* xb = x + (((size_t)b * Cc) << 12) + (h << 6);
#pragma unroll
    for (int it = 0; it < 24; ++it) {
        int j = tid + it * 256;            // 0..6143
        int c = j >> 6, p = j & 63;
        sT[p * 104 + c] = f2bf(xb[((size_t)c << 12) + p]);
    }
    __syncthreads();
    u16* dst = bfm + BF_XTPAD + ((size_t)(b * 66 + h + 1) * 66 + 1) * 96;
#pragma unroll
    for (int it = 0; it < 6; ++it) {
        int j = tid + it * 256;            // 0..1535
        int pos = j / 24, c4 = j % 24;
        const u16* s = &sT[pos * 104 + c4 * 4];
        *(uint2*)(dst + pos * 96 + c4 * 4) = make_uint2(
            (unsigned)s[0] | ((unsigned)s[1] << 16),
            (unsigned)s[2] | ((unsigned)s[3] << 16));
    }
}

// ---------------- xTpad halo zero ----------------
__global__ __launch_bounds__(256) void xhalo_kernel(float* __restrict__ ws)
{
    u16* bfm = (u16*)(ws + FP32_END);
    int i = blockIdx.x * 256 + threadIdx.x;
    if (i >= 4 * 260 * 24) return;
    int c4 = i % 24, rem = i / 24;
    int cell = rem % 260, b = rem / 260;
    int row, col;
    if (cell < 66)       { row = 0;  col = cell; }
    else if (cell < 132) { row = 65; col = cell - 66; }
    else if (cell < 196) { row = cell - 132 + 1; col = 0; }
    else                 { row = cell - 196 + 1; col = 65; }
    u16* dst = bfm + BF_XTPAD + ((size_t)(b * 66 + row) * 66 + col) * 96 + c4 * 4;
    *(uint2*)dst = make_uint2(0u, 0u);
}

// ---------------- offset conv: LDS-staged bf16 MFMA GEMM ----------------
// block: 256 thr (4 waves), N-tile = one image row (64 pos), M = 96 ch (6 frags, grid.y half)
__global__ __launch_bounds__(256) void offconv_mfma(
    const float* __restrict__ ws, float* __restrict__ off)
{
    __shared__ u16 sB[64 * 104];
    const u16* bf = (const u16*)(ws + FP32_END);
    const u16* xp = bf + BF_XTPAD;
    const u16* wof = bf + BF_WOF;
    const int tid = threadIdx.x;
    const int lane = tid & 63, wid = tid >> 6;
    const int lane15 = lane & 15, quad = lane >> 4;
    const int h = blockIdx.x;
    const int f0 = blockIdx.y * 6;
    const int b = blockIdx.z;

    // per-thread coop-load indices (6 uint2 per thread = 64 pos x 96 ch)
    int cj[6], cp[6];
#pragma unroll
    for (int it = 0; it < 6; ++it) {
        int j = tid + it * 256;
        cp[it] = j / 24; cj[it] = (j % 24) * 4;
    }

    uint2 stage[6];
    {   // prefetch tap 0 (ky=-1, kx=-1)
        const u16* src = xp + ((size_t)(b * 66 + h) * 66 + 0) * 96;
#pragma unroll
        for (int it = 0; it < 6; ++it)
            stage[it] = *(const uint2*)(src + cp[it] * 96 + cj[it]);
    }

    f32x4 acc[6];
#pragma unroll
    for (int f = 0; f < 6; ++f) acc[f] = (f32x4){0.f, 0.f, 0.f, 0.f};

    const u16* brow = &sB[(wid * 16 + lane15) * 104 + quad * 8];

    for (int tap = 0; tap < 9; ++tap) {
        __syncthreads();                  // previous compute done
#pragma unroll
        for (int it = 0; it < 6; ++it)
            *(uint2*)(&sB[cp[it] * 104 + cj[it]]) = stage[it];
        __syncthreads();
        if (tap < 8) {                    // prefetch next tap during compute
            int tn = tap + 1;
            int ky = tn / 3 - 1, kx = tn % 3 - 1;
            const u16* src = xp + ((size_t)(b * 66 + h + 1 + ky) * 66 + (1 + kx)) * 96;
#pragma unroll
            for (int it = 0; it < 6; ++it)
                stage[it] = *(const uint2*)(src + cp[it] * 96 + cj[it]);
        }
#pragma unroll
        for (int cc = 0; cc < 3; ++cc) {
            s16x8 bb = *(const s16x8*)(brow + cc * 32);
            const int s = tap * 3 + cc;
#pragma unroll
            for (int f = 0; f < 6; ++f) {
                s16x8 a = *(const s16x8*)(wof + ((size_t)((f0 + f) * 27 + s) * 64 + lane) * 8);
                acc[f] = __builtin_amdgcn_mfma_f32_16x16x32_bf16(a, bb, acc[f], 0, 0, 0);
            }
        }
    }

    const float* bcat = ws + OFF_BCAT;
    const int p = (h << 6) + wid * 16 + lane15;
#pragma unroll
    for (int f = 0; f < 6; ++f) {
        float* dst = off + (((size_t)(b * 192 + (f0 + f) * 16 + quad * 4)) << 12) + p;
#pragma unroll
        for (int r = 0; r < 4; ++r)
            dst[(size_t)r << 12] = acc[f][r] + bcat[(f0 + f) * 16 + quad * 4 + r];
    }
}

// ---------------- deformable sampling: bf16 NHWC gather, bf16 NHWC y ----------------
template<int K>
__device__ __forceinline__ void samp_v4(
    int ksel, int tb, const float* __restrict__ ws, u16* __restrict__ yt)
{
    constexpr int K2 = K * K;
    constexpr int R = (K - 1) / 2;
    __shared__ float soff[2 * 49 * 10];

    const int tid = threadIdx.x;
    const int b = blockIdx.z;
    const int p0 = blockIdx.x * 10;

    const float* offbase = ws + OFF_OFF + ((size_t)(b * 192 + tb)) * HWp;
    for (int i = tid; i < 2 * K2 * 10; i += 256) {
        int t = i / 10, q = i % 10;
        int pp = min(p0 + q, 4095);
        soff[i] = offbase[(size_t)t * HWp + pp];
    }
    __syncthreads();

    if (tid >= 240) return;
    const int c4 = tid % 24;
    const int q  = tid / 24;
    const int p  = p0 + q;
    if (p >= 4096) return;
    const int hh = p >> 6, wp = p & 63;
    const int c = 4 * c4;

    const u16* xb = (const u16*)(ws + FP32_END) + BF_XTPAD + (size_t)b * 66 * 66 * 96;
    const float* wdT = ws + OFF_WDWT + ksel * 4704 + c;

    float4 acc = make_float4(0.f, 0.f, 0.f, 0.f);

#pragma unroll 2
    for (int t = 0; t < K2; ++t) {
        const int ky = t / K - R;
        const int kx = t % K - R;
        float dy = soff[t * 10 + q];
        float dx = soff[(K2 + t) * 10 + q];
        float py = fminf(fmaxf((float)(hh + ky) + dy, 0.f), 63.f);
        float px = fminf(fmaxf((float)(wp + kx) + dx, 0.f), 63.f);
        float fy = floorf(py), fx = floorf(px);
        int y0 = (int)fy, x0 = (int)fx;
        float wy = py - fy, wx = px - fx;
        int y1 = min(y0 + 1, 63), x1 = min(x0 + 1, 63);
        float w11 = wy * wx;
        float w10 = wy - w11;
        float w01 = wx - w11;
        float w00 = 1.f - wy - wx + w11;
        const uint2 u00 = *(const uint2*)(xb + ((size_t)((y0 + 1) * 66 + (x0 + 1))) * 96 + c);
        const uint2 u01 = *(const uint2*)(xb + ((size_t)((y0 + 1) * 66 + (x1 + 1))) * 96 + c);
        const uint2 u10 = *(const uint2*)(xb + ((size_t)((y1 + 1) * 66 + (x0 + 1))) * 96 + c);
        const uint2 u11 = *(const uint2*)(xb + ((size_t)((y1 + 1) * 66 + (x1 + 1))) * 96 + c);
        const float4 wd = *(const float4*)(wdT + t * 96);
        float v0 = fmaf(w00, bflo(u00.x), fmaf(w01, bflo(u01.x), fmaf(w10, bflo(u10.x), w11 * bflo(u11.x))));
        float v1 = fmaf(w00, bfhi(u00.x), fmaf(w01, bfhi(u01.x), fmaf(w10, bfhi(u10.x), w11 * bfhi(u11.x))));
        float v2 = fmaf(w00, bflo(u00.y), fmaf(w01, bflo(u01.y), fmaf(w10, bflo(u10.y), w11 * bflo(u11.y))));
        float v3 = fmaf(w00, bfhi(u00.y), fmaf(w01, bfhi(u01.y), fmaf(w10, bfhi(u10.y), w11 * bfhi(u11.y))));
        acc.x = fmaf(wd.x, v0, acc.x);
        acc.y = fmaf(wd.y, v1, acc.y);
        acc.z = fmaf(wd.z, v2, acc.z);
        acc.w = fmaf(wd.w, v3, acc.w);
    }

    const int cb = ksel * Cc + c;
    const float4 s4 = *(const float4*)(ws + OFF_SBR + cb);
    const float4 h4 = *(const float4*)(ws + OFF_HBR + cb);
    u16 r0 = f2bf(fmaxf(fmaf(acc.x, s4.x, h4.x), 0.f));
    u16 r1 = f2bf(fmaxf(fmaf(acc.y, s4.y, h4.y), 0.f));
    u16 r2 = f2bf(fmaxf(fmaf(acc.z, s4.z, h4.z), 0.f));
    u16 r3 = f2bf(fmaxf(fmaf(acc.w, s4.w, h4.w), 0.f));
    u16* dst = yt + ((size_t)(b << 12) + p) * C3 + cb;
    *(uint2*)dst = make_uint2((unsigned)r0 | ((unsigned)r1 << 16),
                              (unsigned)r2 | ((unsigned)r3 << 16));
}

__global__ __launch_bounds__(256) void sampdw4_kernel(float* __restrict__ ws)
{
    u16* yt = (u16*)(ws + FP32_END) + BF_YT;
    const int e = blockIdx.y;
    if (e == 0)      samp_v4<3>(0, 0,  ws, yt);
    else if (e == 1) samp_v4<5>(1, 18, ws, yt);
    else             samp_v4<7>(2, 68, ws, yt);
}

// ---------------- pointwise: LDS-staged bf16 MFMA GEMM + BN + ReLU ----------------
// block: 256 thr (4 waves), N-tile 64 pos, M = 96 out (6 frags, grid.y half), K = 288
__global__ __launch_bounds__(256) void pwconv_mfma(
    const float* __restrict__ ws, float* __restrict__ out)
{
    __shared__ u16 sB[64 * 296];
    const u16* bf = (const u16*)(ws + FP32_END);
    const u16* yt = bf + BF_YT;
    const u16* wpw = bf + BF_WPW;
    const int tid = threadIdx.x;
    const int lane = tid & 63, wid = tid >> 6;
    const int lane15 = lane & 15, quad = lane >> 4;
    const int p0 = blockIdx.x * 64;
    const int f0 = blockIdx.y * 6;
    const int b = blockIdx.z;

#pragma unroll
    for (int it = 0; it < 9; ++it) {
        int j = tid + it * 256;            // 0..2303
        int pos = j / 36, c8 = j % 36;
        *(uint4*)(&sB[pos * 296 + c8 * 8]) =
            *(const uint4*)(yt + ((size_t)(b << 12) + p0 + pos) * C3 + c8 * 8);
    }
    __syncthreads();

    f32x4 acc[6];
#pragma unroll
    for (int f = 0; f < 6; ++f) acc[f] = (f32x4){0.f, 0.f, 0.f, 0.f};

    const u16* brow = &sB[(wid * 16 + lane15) * 296 + quad * 8];
#pragma unroll
    for (int s = 0; s < 9; ++s) {
        s16x8 bb = *(const s16x8*)(brow + s * 32);
#pragma unroll
        for (int f = 0; f < 6; ++f) {
            s16x8 a = *(const s16x8*)(wpw + ((size_t)((f0 + f) * 9 + s) * 64 + lane) * 8);
            acc[f] = __builtin_amdgcn_mfma_f32_16x16x32_bf16(a, bb, acc[f], 0, 0, 0);
        }
    }

    const float* spw = ws + OFF_SPW;
    const float* hpw = ws + OFF_HPW;
    const int p = p0 + wid * 16 + lane15;
#pragma unroll
    for (int f = 0; f < 6; ++f) {
        float* dst = out + (((size_t)(b * Oo + (f0 + f) * 16 + quad * 4)) << 12) + p;
#pragma unroll
        for (int r = 0; r < 4; ++r) {
            int o = (f0 + f) * 16 + quad * 4 + r;
            dst[(size_t)r << 12] = fmaxf(fmaf(acc[f][r], spw[o], hpw[o]), 0.f);
        }
    }
}

extern "C" void kernel_launch(void* const* d_in, const int* in_sizes, int n_in,
                              void* d_out, int out_size, void* d_ws, size_t ws_size,
                              hipStream_t stream)
{
    const float* x     = (const float*)d_in[0];
    const float* w3    = (const float*)d_in[1];
    const float* b3    = (const float*)d_in[2];
    const float* dw3   = (const float*)d_in[3];
    const float* g3    = (const float*)d_in[4];
    const float* be3   = (const float*)d_in[5];
    const float* m3    = (const float*)d_in[6];
    const float* v3    = (const float*)d_in[7];
    const float* w5    = (const float*)d_in[8];
    const float* b5    = (const float*)d_in[9];
    const float* dw5   = (const float*)d_in[10];
    const float* g5    = (const float*)d_in[11];
    const float* be5   = (const float*)d_in[12];
    const float* m5    = (const float*)d_in[13];
    const float* v5    = (const float*)d_in[14];
    const float* w7    = (const float*)d_in[15];
    const float* b7    = (const float*)d_in[16];
    const float* dw7   = (const float*)d_in[17];
    const float* g7    = (const float*)d_in[18];
    const float* be7   = (const float*)d_in[19];
    const float* m7    = (const float*)d_in[20];
    const float* v7    = (const float*)d_in[21];
    const float* wpw   = (const float*)d_in[22];
    const float* gp    = (const float*)d_in[23];
    const float* bp    = (const float*)d_in[24];
    const float* mp    = (const float*)d_in[25];
    const float* vp    = (const float*)d_in[26];

    float* ws = (float*)d_ws;
    float* out = (float*)d_out;

    {   // 1) prep
        prep_kernel<<<(PREP_N + 255) / 256, 256, 0, stream>>>(
            w3, b3, dw3, g3, be3, m3, v3,
            w5, b5, dw5, g5, be5, m5, v5,
            w7, b7, dw7, g7, be7, m7, v7,
            wpw, gp, bp, mp, vp, ws);
    }
    {   // 1b) halo zero + interior transpose
        xhalo_kernel<<<(4 * 260 * 24 + 255) / 256, 256, 0, stream>>>(ws);
        dim3 grid(64, Bb);
        xtpad_kernel<<<grid, 256, 0, stream>>>(x, ws);
    }
    {   // 2) fused offset conv (LDS-staged MFMA)
        dim3 grid(64, 2, Bb);
        offconv_mfma<<<grid, 256, 0, stream>>>(ws, ws + OFF_OFF);
    }
    {   // 3) deformable sampling + depthwise + BN + ReLU
        dim3 grid(410, 3, Bb);
        sampdw4_kernel<<<grid, 256, 0, stream>>>(ws);
    }
    {   // 4) pointwise (LDS-staged MFMA) + BN + ReLU
        dim3 grid(64, 2, Bb);
        pwconv_mfma<<<grid, 256, 0, stream>>>(ws, out);
    }
}

// Round 6
// 238.356 us; speedup vs baseline: 2.6302x; 1.1102x over previous
//
#include <hip/hip_runtime.h>
#include <math.h>

typedef unsigned short u16;
typedef short s16x8 __attribute__((ext_vector_type(8)));
typedef float f32x4 __attribute__((ext_vector_type(4)));

#define HWp 4096
#define Cc 96
#define Bb 4
#define Oo 192
#define C3 288

// ---------- fp32 workspace region (float offsets) ----------
#define OFF_OFF   0           // [4][192][4096] (rows 166..191 scratch)
#define OFF_WDWT  3145728     // [3][49][96]
#define OFF_BCAT  3159840     // [192]
#define OFF_SBR   3160032     // [288]
#define OFF_HBR   3160320     // [288]
#define OFF_SPW   3160608     // [192]
#define OFF_HPW   3160800     // [192]
#define FP32_END  3160992
// ---------- bf16 region (u16 offsets, base = ws + FP32_END) ----------
#define BF_XTPAD  0           // [4][66][66][96]
#define BF_WOF    1672704     // 12 frag x 27 step x 64 lane x 8
#define BF_WPW    1838592     // 12 frag x 9 step x 64 lane x 8
#define BF_YT     1893888     // [4][4096][288]

__device__ __forceinline__ u16 f2bf(float f) {
    union { float f; unsigned u; } t; t.f = f;
    unsigned u = t.u;
    return (u16)((u + 0x7fffu + ((u >> 16) & 1u)) >> 16);
}
__device__ __forceinline__ float bflo(unsigned u) { return __uint_as_float(u << 16); }
__device__ __forceinline__ float bfhi(unsigned u) { return __uint_as_float(u & 0xffff0000u); }

// ---------------- prep: repack weights, fold BN, zero halo ----------------
__global__ __launch_bounds__(256) void prep_kernel(
    const float* __restrict__ w3, const float* __restrict__ b3, const float* __restrict__ dw3,
    const float* __restrict__ g3, const float* __restrict__ be3, const float* __restrict__ m3, const float* __restrict__ v3,
    const float* __restrict__ w5, const float* __restrict__ b5, const float* __restrict__ dw5,
    const float* __restrict__ g5, const float* __restrict__ be5, const float* __restrict__ m5, const float* __restrict__ v5,
    const float* __restrict__ w7, const float* __restrict__ b7, const float* __restrict__ dw7,
    const float* __restrict__ g7, const float* __restrict__ be7, const float* __restrict__ m7, const float* __restrict__ v7,
    const float* __restrict__ wpw,
    const float* __restrict__ gp, const float* __restrict__ bp, const float* __restrict__ mp, const float* __restrict__ vp,
    float* __restrict__ ws)
{
    u16* bf = (u16*)(ws + FP32_END);
    int i = blockIdx.x * 256 + threadIdx.x;
    if (i < 165888) {                       // WOF frag-linear bf16, 12 m-frags
        int f = i / 13824, r = i % 13824;
        int s = r >> 9, l = r & 511;
        int lane = l >> 3, j = l & 7;
        int o = f * 16 + (lane & 15);
        int k = s * 32 + (lane >> 4) * 8 + j;   // k = tap*96 + c
        int tap = k / 96, c = k % 96;
        float v = 0.f;
        if (o < 18)       v = w3[o * 864 + c * 9 + tap];
        else if (o < 68)  v = w5[(o - 18) * 864 + c * 9 + tap];
        else if (o < 166) v = w7[(o - 68) * 864 + c * 9 + tap];
        bf[BF_WOF + i] = f2bf(v);
        return;
    }
    int j = i - 165888;
    if (j < 55296) {                        // WPW frag-linear bf16
        int f = j / 4608, r = j % 4608;
        int s = r >> 9, l = r & 511;
        int lane = l >> 3, jj = l & 7;
        int o = f * 16 + (lane & 15);
        int k = s * 32 + (lane >> 4) * 8 + jj;
        bf[BF_WPW + j] = f2bf(wpw[o * C3 + k]);
        return;
    }
    j -= 55296;
    if (j < 14112) {                        // wdwT [3][49][96] fp32
        int ksel = j / 4704, rem = j % 4704;
        int t = rem / 96, c = rem % 96;
        int K2 = (ksel == 0) ? 9 : (ksel == 1) ? 25 : 49;
        const float* dw = (ksel == 0) ? dw3 : (ksel == 1) ? dw5 : dw7;
        ws[OFF_WDWT + j] = (t < K2) ? dw[c * K2 + t] : 0.f;
        return;
    }
    j -= 14112;
    if (j < 192) {                          // bcat (padded)
        float v = 0.f;
        if (j < 18)       v = b3[j];
        else if (j < 68)  v = b5[j - 18];
        else if (j < 166) v = b7[j - 68];
        ws[OFF_BCAT + j] = v;
        return;
    }
    j -= 192;
    if (j < C3) {                           // sbr
        int ks = j / Cc, c = j % Cc;
        const float* g = (ks == 0) ? g3 : (ks == 1) ? g5 : g7;
        const float* v = (ks == 0) ? v3 : (ks == 1) ? v5 : v7;
        ws[OFF_SBR + j] = g[c] / sqrtf(v[c] + 1e-5f);
        return;
    }
    j -= C3;
    if (j < C3) {                           // hbr
        int ks = j / Cc, c = j % Cc;
        const float* g = (ks == 0) ? g3 : (ks == 1) ? g5 : g7;
        const float* v = (ks == 0) ? v3 : (ks == 1) ? v5 : v7;
        const float* be = (ks == 0) ? be3 : (ks == 1) ? be5 : be7;
        const float* m = (ks == 0) ? m3 : (ks == 1) ? m5 : m7;
        float inv = g[c] / sqrtf(v[c] + 1e-5f);
        ws[OFF_HBR + j] = be[c] - m[c] * inv;
        return;
    }
    j -= C3;
    if (j < Oo) { ws[OFF_SPW + j] = gp[j] / sqrtf(vp[j] + 1e-5f); return; }
    j -= Oo;
    if (j < Oo) {
        float inv = gp[j] / sqrtf(vp[j] + 1e-5f);
        ws[OFF_HPW + j] = bp[j] - mp[j] * inv;
        return;
    }
    j -= Oo;
    if (j < 24960) {                        // xTpad halo zero: 4 b x 260 cells x 24 c4
        int c4 = j % 24, rem = j / 24;
        int cell = rem % 260, bb = rem / 260;
        int row, col;
        if (cell < 66)       { row = 0;  col = cell; }
        else if (cell < 132) { row = 65; col = cell - 66; }
        else if (cell < 196) { row = cell - 132 + 1; col = 0; }
        else                 { row = cell - 196 + 1; col = 65; }
        u16* dst = bf + BF_XTPAD + ((size_t)(bb * 66 + row) * 66 + col) * 96 + c4 * 4;
        *(uint2*)dst = make_uint2(0u, 0u);
        return;
    }
}
#define PREP_N (165888 + 55296 + 14112 + 192 + 288 + 288 + 192 + 192 + 24960)

// ---------------- xTpad interior: coalesced LDS transpose ----------------
__global__ __launch_bounds__(256) void xtpad_kernel(
    const float* __restrict__ x, float* __restrict__ ws)
{
    __shared__ u16 sT[64 * 104];
    u16* bfm = (u16*)(ws + FP32_END);
    const int tid = threadIdx.x;
    const int h = blockIdx.x, b = blockIdx.y;
    const float* xb = x + (((size_t)b * Cc) << 12) + (h << 6);
#pragma unroll
    for (int it = 0; it < 24; ++it) {
        int j = tid + it * 256;            // 0..6143
        int c = j >> 6, p = j & 63;
        sT[p * 104 + c] = f2bf(xb[((size_t)c << 12) + p]);
    }
    __syncthreads();
    u16* dst = bfm + BF_XTPAD + ((size_t)(b * 66 + h + 1) * 66 + 1) * 96;
#pragma unroll
    for (int it = 0; it < 6; ++it) {
        int j = tid + it * 256;            // 0..1535
        int pos = j / 24, c4 = j % 24;
        const u16* s = &sT[pos * 104 + c4 * 4];
        *(uint2*)(dst + pos * 96 + c4 * 4) = make_uint2(
            (unsigned)s[0] | ((unsigned)s[1] << 16),
            (unsigned)s[2] | ((unsigned)s[3] << 16));
    }
}

// ---------------- offset conv v2: 3-row LDS-resident strip, one barrier ----------------
// block: 256 thr (4 waves), N = one image row (64 pos), M = 96 co (6 frags, grid.y half)
__global__ __launch_bounds__(256) void offconv_mfma(
    const float* __restrict__ ws, float* __restrict__ off)
{
    __shared__ u16 sX[3 * 66 * 98];        // [r][col][98-padded ch] -> conflict-free ds_read_b128
    const u16* bf = (const u16*)(ws + FP32_END);
    const u16* xp = bf + BF_XTPAD;
    const u16* wof = bf + BF_WOF;
    const int tid = threadIdx.x;
    const int lane = tid & 63, wid = tid >> 6;
    const int lane15 = lane & 15, quad = lane >> 4;
    const int h = blockIdx.x;
    const int f0 = blockIdx.y * 6;
    const int b = blockIdx.z;

    // coop load rows h-1..h+1 (padded rows h..h+2), 66 cols x 96 ch
#pragma unroll
    for (int it = 0; it < 19; ++it) {
        int j = tid + it * 256;            // uint2 chunks: 3*66*24 = 4752
        if (j < 4752) {
            int r = j / (66 * 24);
            int rem = j % (66 * 24);
            int col = rem / 24, c4 = rem % 24;
            uint2 v = *(const uint2*)(xp + ((size_t)((b * 66 + h + r) * 66 + col)) * 96 + c4 * 4);
            *(uint2*)(&sX[(r * 66 + col) * 98 + c4 * 4]) = v;
        }
    }
    __syncthreads();

    f32x4 acc[6];
#pragma unroll
    for (int f = 0; f < 6; ++f) acc[f] = (f32x4){0.f, 0.f, 0.f, 0.f};

    const int pos = wid * 16 + lane15;
#pragma unroll
    for (int tap = 0; tap < 9; ++tap) {
        const int ky = tap / 3, kx = tap % 3;
        const u16* brow = &sX[(ky * 66 + kx + pos) * 98 + quad * 8];
#pragma unroll
        for (int cc = 0; cc < 3; ++cc) {
            s16x8 bb = *(const s16x8*)(brow + cc * 32);
            const int s = tap * 3 + cc;
#pragma unroll
            for (int f = 0; f < 6; ++f) {
                s16x8 a = *(const s16x8*)(wof + ((size_t)((f0 + f) * 27 + s) * 64 + lane) * 8);
                acc[f] = __builtin_amdgcn_mfma_f32_16x16x32_bf16(a, bb, acc[f], 0, 0, 0);
            }
        }
    }

    const float* bcat = ws + OFF_BCAT;
    const int p = (h << 6) + pos;
#pragma unroll
    for (int f = 0; f < 6; ++f) {
        float* dst = off + (((size_t)(b * 192 + (f0 + f) * 16 + quad * 4)) << 12) + p;
#pragma unroll
        for (int r = 0; r < 4; ++r)
            dst[(size_t)r << 12] = acc[f][r] + bcat[(f0 + f) * 16 + quad * 4 + r];
    }
}

// ---------------- deformable sampling v5 ----------------
// phase 1: per (tap, position) bilinear weights + corner offsets -> LDS (shared by 12 ch-lanes)
// phase 2: lane = 8 channels (uint4 gathers), 20 positions/block
template<int K>
__device__ __forceinline__ void samp_v5(
    int ksel, const float* __restrict__ ws, u16* __restrict__ yt)
{
    constexpr int K2 = K * K;
    constexpr int R = (K - 1) / 2;
    const int tb = (ksel == 0) ? 0 : ((ksel == 1) ? 18 : 68);
    __shared__ float sWI[49 * 20 * 8];

    const int tid = threadIdx.x;
    const int b = blockIdx.z;
    const int p0 = blockIdx.x * 20;

    const float* offb = ws + OFF_OFF + ((size_t)(b * 192 + tb)) * HWp;
    for (int i = tid; i < K2 * 20; i += 256) {
        int t = i / 20, q = i % 20;
        int p = min(p0 + q, 4095);
        int hh = p >> 6, wp = p & 63;
        float dy = offb[(size_t)t * HWp + p];
        float dx = offb[(size_t)(K2 + t) * HWp + p];
        int ky = t / K - R, kx = t % K - R;
        float py = fminf(fmaxf((float)(hh + ky) + dy, 0.f), 63.f);
        float px = fminf(fmaxf((float)(wp + kx) + dx, 0.f), 63.f);
        float fy = floorf(py), fx = floorf(px);
        int y0 = (int)fy, x0 = (int)fx;
        float wy = py - fy, wx = px - fx;
        int y1 = min(y0 + 1, 63), x1 = min(x0 + 1, 63);
        float w11 = wy * wx;
        float w10 = wy - w11;
        float w01 = wx - w11;
        float w00 = 1.f - wy - wx + w11;
        float* dst = &sWI[i * 8];
        dst[0] = w00; dst[1] = w01; dst[2] = w10; dst[3] = w11;
        dst[4] = __int_as_float(((y0 + 1) * 66 + x0 + 1) * 96);
        dst[5] = __int_as_float(((y0 + 1) * 66 + x1 + 1) * 96);
        dst[6] = __int_as_float(((y1 + 1) * 66 + x0 + 1) * 96);
        dst[7] = __int_as_float(((y1 + 1) * 66 + x1 + 1) * 96);
    }
    __syncthreads();

    if (tid >= 240) return;
    const int c8 = tid % 12;
    const int q  = tid / 12;
    const int p  = p0 + q;
    if (p >= 4096) return;
    const int c = c8 * 8;

    const u16* xc = (const u16*)(ws + FP32_END) + BF_XTPAD + (size_t)b * 66 * 66 * 96 + c;
    const float* wdT = ws + OFF_WDWT + ksel * 4704 + c;

    float acc[8];
#pragma unroll
    for (int k = 0; k < 8; ++k) acc[k] = 0.f;

    for (int t = 0; t < K2; ++t) {
        const float4 W = *(const float4*)(&sWI[(t * 20 + q) * 8]);
        const float4 I = *(const float4*)(&sWI[(t * 20 + q) * 8 + 4]);
        const uint4 u00 = *(const uint4*)(xc + __float_as_int(I.x));
        const uint4 u01 = *(const uint4*)(xc + __float_as_int(I.y));
        const uint4 u10 = *(const uint4*)(xc + __float_as_int(I.z));
        const uint4 u11 = *(const uint4*)(xc + __float_as_int(I.w));
        const float4 wda = *(const float4*)(wdT + t * 96);
        const float4 wdb = *(const float4*)(wdT + t * 96 + 4);
        const unsigned a00[4] = {u00.x, u00.y, u00.z, u00.w};
        const unsigned a01[4] = {u01.x, u01.y, u01.z, u01.w};
        const unsigned a10[4] = {u10.x, u10.y, u10.z, u10.w};
        const unsigned a11[4] = {u11.x, u11.y, u11.z, u11.w};
        const float wd[8] = {wda.x, wda.y, wda.z, wda.w, wdb.x, wdb.y, wdb.z, wdb.w};
#pragma unroll
        for (int d = 0; d < 4; ++d) {
            float vlo = fmaf(W.x, bflo(a00[d]), fmaf(W.y, bflo(a01[d]),
                        fmaf(W.z, bflo(a10[d]), W.w * bflo(a11[d]))));
            float vhi = fmaf(W.x, bfhi(a00[d]), fmaf(W.y, bfhi(a01[d]),
                        fmaf(W.z, bfhi(a10[d]), W.w * bfhi(a11[d]))));
            acc[2 * d]     = fmaf(wd[2 * d],     vlo, acc[2 * d]);
            acc[2 * d + 1] = fmaf(wd[2 * d + 1], vhi, acc[2 * d + 1]);
        }
    }

    const int cb = ksel * Cc + c;
    const float4 sa = *(const float4*)(ws + OFF_SBR + cb);
    const float4 sb = *(const float4*)(ws + OFF_SBR + cb + 4);
    const float4 ha = *(const float4*)(ws + OFF_HBR + cb);
    const float4 hb = *(const float4*)(ws + OFF_HBR + cb + 4);
    const float ss[8] = {sa.x, sa.y, sa.z, sa.w, sb.x, sb.y, sb.z, sb.w};
    const float hh8[8] = {ha.x, ha.y, ha.z, ha.w, hb.x, hb.y, hb.z, hb.w};
    unsigned r[4];
#pragma unroll
    for (int d = 0; d < 4; ++d) {
        u16 lo = f2bf(fmaxf(fmaf(acc[2 * d],     ss[2 * d],     hh8[2 * d]),     0.f));
        u16 hi = f2bf(fmaxf(fmaf(acc[2 * d + 1], ss[2 * d + 1], hh8[2 * d + 1]), 0.f));
        r[d] = (unsigned)lo | ((unsigned)hi << 16);
    }
    *(uint4*)(yt + ((size_t)(b << 12) + p) * C3 + cb) = make_uint4(r[0], r[1], r[2], r[3]);
}

__global__ __launch_bounds__(256) void sampdw5_kernel(float* __restrict__ ws)
{
    u16* yt = (u16*)(ws + FP32_END) + BF_YT;
    const int e = blockIdx.y;
    if (e == 0)      samp_v5<3>(0, ws, yt);
    else if (e == 1) samp_v5<5>(1, ws, yt);
    else             samp_v5<7>(2, ws, yt);
}

// ---------------- pointwise: LDS-staged bf16 MFMA GEMM + BN + ReLU ----------------
__global__ __launch_bounds__(256) void pwconv_mfma(
    const float* __restrict__ ws, float* __restrict__ out)
{
    __shared__ u16 sB[64 * 296];
    const u16* bf = (const u16*)(ws + FP32_END);
    const u16* yt = bf + BF_YT;
    const u16* wpw = bf + BF_WPW;
    const int tid = threadIdx.x;
    const int lane = tid & 63, wid = tid >> 6;
    const int lane15 = lane & 15, quad = lane >> 4;
    const int p0 = blockIdx.x * 64;
    const int f0 = blockIdx.y * 6;
    const int b = blockIdx.z;

#pragma unroll
    for (int it = 0; it < 9; ++it) {
        int j = tid + it * 256;            // 0..2303
        int pos = j / 36, c8 = j % 36;
        *(uint4*)(&sB[pos * 296 + c8 * 8]) =
            *(const uint4*)(yt + ((size_t)(b << 12) + p0 + pos) * C3 + c8 * 8);
    }
    __syncthreads();

    f32x4 acc[6];
#pragma unroll
    for (int f = 0; f < 6; ++f) acc[f] = (f32x4){0.f, 0.f, 0.f, 0.f};

    const u16* brow = &sB[(wid * 16 + lane15) * 296 + quad * 8];
#pragma unroll
    for (int s = 0; s < 9; ++s) {
        s16x8 bb = *(const s16x8*)(brow + s * 32);
#pragma unroll
        for (int f = 0; f < 6; ++f) {
            s16x8 a = *(const s16x8*)(wpw + ((size_t)((f0 + f) * 9 + s) * 64 + lane) * 8);
            acc[f] = __builtin_amdgcn_mfma_f32_16x16x32_bf16(a, bb, acc[f], 0, 0, 0);
        }
    }

    const float* spw = ws + OFF_SPW;
    const float* hpw = ws + OFF_HPW;
    const int p = p0 + wid * 16 + lane15;
#pragma unroll
    for (int f = 0; f < 6; ++f) {
        float* dst = out + (((size_t)(b * Oo + (f0 + f) * 16 + quad * 4)) << 12) + p;
#pragma unroll
        for (int r = 0; r < 4; ++r) {
            int o = (f0 + f) * 16 + quad * 4 + r;
            dst[(size_t)r << 12] = fmaxf(fmaf(acc[f][r], spw[o], hpw[o]), 0.f);
        }
    }
}

extern "C" void kernel_launch(void* const* d_in, const int* in_sizes, int n_in,
                              void* d_out, int out_size, void* d_ws, size_t ws_size,
                              hipStream_t stream)
{
    const float* x     = (const float*)d_in[0];
    const float* w3    = (const float*)d_in[1];
    const float* b3    = (const float*)d_in[2];
    const float* dw3   = (const float*)d_in[3];
    const float* g3    = (const float*)d_in[4];
    const float* be3   = (const float*)d_in[5];
    const float* m3    = (const float*)d_in[6];
    const float* v3    = (const float*)d_in[7];
    const float* w5    = (const float*)d_in[8];
    const float* b5    = (const float*)d_in[9];
    const float* dw5   = (const float*)d_in[10];
    const float* g5    = (const float*)d_in[11];
    const float* be5   = (const float*)d_in[12];
    const float* m5    = (const float*)d_in[13];
    const float* v5    = (const float*)d_in[14];
    const float* w7    = (const float*)d_in[15];
    const float* b7    = (const float*)d_in[16];
    const float* dw7   = (const float*)d_in[17];
    const float* g7    = (const float*)d_in[18];
    const float* be7   = (const float*)d_in[19];
    const float* m7    = (const float*)d_in[20];
    const float* v7    = (const float*)d_in[21];
    const float* wpw   = (const float*)d_in[22];
    const float* gp    = (const float*)d_in[23];
    const float* bp    = (const float*)d_in[24];
    const float* mp    = (const float*)d_in[25];
    const float* vp    = (const float*)d_in[26];

    float* ws = (float*)d_ws;
    float* out = (float*)d_out;

    {   // 1) prep (+ halo zero)
        prep_kernel<<<(PREP_N + 255) / 256, 256, 0, stream>>>(
            w3, b3, dw3, g3, be3, m3, v3,
            w5, b5, dw5, g5, be5, m5, v5,
            w7, b7, dw7, g7, be7, m7, v7,
            wpw, gp, bp, mp, vp, ws);
    }
    {   // 1b) interior transpose
        dim3 grid(64, Bb);
        xtpad_kernel<<<grid, 256, 0, stream>>>(x, ws);
    }
    {   // 2) fused offset conv (LDS-resident strip MFMA)
        dim3 grid(64, 2, Bb);
        offconv_mfma<<<grid, 256, 0, stream>>>(ws, ws + OFF_OFF);
    }
    {   // 3) deformable sampling + depthwise + BN + ReLU
        dim3 grid(205, 3, Bb);
        sampdw5_kernel<<<grid, 256, 0, stream>>>(ws);
    }
    {   // 4) pointwise (LDS-staged MFMA) + BN + ReLU
        dim3 grid(64, 2, Bb);
        pwconv_mfma<<<grid, 256, 0, stream>>>(ws, out);
    }
}

// Round 8
// 208.864 us; speedup vs baseline: 3.0016x; 1.1412x over previous
//
#include <hip/hip_runtime.h>
#include <math.h>

typedef unsigned short u16;
typedef short s16x8 __attribute__((ext_vector_type(8)));
typedef float f32x4 __attribute__((ext_vector_type(4)));

#define HWp 4096
#define Cc 96
#define Bb 4
#define Oo 192
#define C3 288

// ---------- fp32 workspace region (float offsets) ----------
#define OFF_OFF   0           // [4][192][4096] (rows 166..191 scratch)
#define OFF_WDWT  3145728     // [3][49][96]
#define OFF_BCAT  3159840     // [192]
#define OFF_SBR   3160032     // [288]
#define OFF_HBR   3160320     // [288]
#define OFF_SPW   3160608     // [192]
#define OFF_HPW   3160800     // [192]
#define FP32_END  3160992
// ---------- bf16 region (u16 offsets, base = ws + FP32_END) ----------
#define BF_XTPAD  0           // [4][66][66][96]
#define BF_WOF    1672704     // 12 frag x 27 step x 64 lane x 8
#define BF_WPW    1838592     // 12 frag x 9 step x 64 lane x 8
#define BF_YT     1893888     // [4][4096][288]

__device__ __forceinline__ u16 f2bf(float f) {
    union { float f; unsigned u; } t; t.f = f;
    unsigned u = t.u;
    return (u16)((u + 0x7fffu + ((u >> 16) & 1u)) >> 16);
}
__device__ __forceinline__ float bflo(unsigned u) { return __uint_as_float(u << 16); }
__device__ __forceinline__ float bfhi(unsigned u) { return __uint_as_float(u & 0xffff0000u); }

// ---------------- prep: repack weights, fold BN, zero halo ----------------
__global__ __launch_bounds__(256) void prep_kernel(
    const float* __restrict__ w3, const float* __restrict__ b3, const float* __restrict__ dw3,
    const float* __restrict__ g3, const float* __restrict__ be3, const float* __restrict__ m3, const float* __restrict__ v3,
    const float* __restrict__ w5, const float* __restrict__ b5, const float* __restrict__ dw5,
    const float* __restrict__ g5, const float* __restrict__ be5, const float* __restrict__ m5, const float* __restrict__ v5,
    const float* __restrict__ w7, const float* __restrict__ b7, const float* __restrict__ dw7,
    const float* __restrict__ g7, const float* __restrict__ be7, const float* __restrict__ m7, const float* __restrict__ v7,
    const float* __restrict__ wpw,
    const float* __restrict__ gp, const float* __restrict__ bp, const float* __restrict__ mp, const float* __restrict__ vp,
    float* __restrict__ ws)
{
    u16* bf = (u16*)(ws + FP32_END);
    int i = blockIdx.x * 256 + threadIdx.x;
    if (i < 165888) {                       // WOF frag-linear bf16, 12 m-frags
        int f = i / 13824, r = i % 13824;
        int s = r >> 9, l = r & 511;
        int lane = l >> 3, j = l & 7;
        int o = f * 16 + (lane & 15);
        int k = s * 32 + (lane >> 4) * 8 + j;   // k = tap*96 + c
        int tap = k / 96, c = k % 96;
        float v = 0.f;
        if (o < 18)       v = w3[o * 864 + c * 9 + tap];
        else if (o < 68)  v = w5[(o - 18) * 864 + c * 9 + tap];
        else if (o < 166) v = w7[(o - 68) * 864 + c * 9 + tap];
        bf[BF_WOF + i] = f2bf(v);
        return;
    }
    int j = i - 165888;
    if (j < 55296) {                        // WPW frag-linear bf16
        int f = j / 4608, r = j % 4608;
        int s = r >> 9, l = r & 511;
        int lane = l >> 3, jj = l & 7;
        int o = f * 16 + (lane & 15);
        int k = s * 32 + (lane >> 4) * 8 + jj;
        bf[BF_WPW + j] = f2bf(wpw[o * C3 + k]);
        return;
    }
    j -= 55296;
    if (j < 14112) {                        // wdwT [3][49][96] fp32
        int ksel = j / 4704, rem = j % 4704;
        int t = rem / 96, c = rem % 96;
        int K2 = (ksel == 0) ? 9 : (ksel == 1) ? 25 : 49;
        const float* dw = (ksel == 0) ? dw3 : (ksel == 1) ? dw5 : dw7;
        ws[OFF_WDWT + j] = (t < K2) ? dw[c * K2 + t] : 0.f;
        return;
    }
    j -= 14112;
    if (j < 192) {                          // bcat (padded)
        float v = 0.f;
        if (j < 18)       v = b3[j];
        else if (j < 68)  v = b5[j - 18];
        else if (j < 166) v = b7[j - 68];
        ws[OFF_BCAT + j] = v;
        return;
    }
    j -= 192;
    if (j < C3) {                           // sbr
        int ks = j / Cc, c = j % Cc;
        const float* g = (ks == 0) ? g3 : (ks == 1) ? g5 : g7;
        const float* v = (ks == 0) ? v3 : (ks == 1) ? v5 : v7;
        ws[OFF_SBR + j] = g[c] / sqrtf(v[c] + 1e-5f);
        return;
    }
    j -= C3;
    if (j < C3) {                           // hbr
        int ks = j / Cc, c = j % Cc;
        const float* g = (ks == 0) ? g3 : (ks == 1) ? g5 : g7;
        const float* v = (ks == 0) ? v3 : (ks == 1) ? v5 : v7;
        const float* be = (ks == 0) ? be3 : (ks == 1) ? be5 : be7;
        const float* m = (ks == 0) ? m3 : (ks == 1) ? m5 : m7;
        float inv = g[c] / sqrtf(v[c] + 1e-5f);
        ws[OFF_HBR + j] = be[c] - m[c] * inv;
        return;
    }
    j -= C3;
    if (j < Oo) { ws[OFF_SPW + j] = gp[j] / sqrtf(vp[j] + 1e-5f); return; }
    j -= Oo;
    if (j < Oo) {
        float inv = gp[j] / sqrtf(vp[j] + 1e-5f);
        ws[OFF_HPW + j] = bp[j] - mp[j] * inv;
        return;
    }
    j -= Oo;
    if (j < 24960) {                        // xTpad halo zero: 4 b x 260 cells x 24 c4
        int c4 = j % 24, rem = j / 24;
        int cell = rem % 260, bb = rem / 260;
        int row, col;
        if (cell < 66)       { row = 0;  col = cell; }
        else if (cell < 132) { row = 65; col = cell - 66; }
        else if (cell < 196) { row = cell - 132 + 1; col = 0; }
        else                 { row = cell - 196 + 1; col = 65; }
        u16* dst = bf + BF_XTPAD + ((size_t)(bb * 66 + row) * 66 + col) * 96 + c4 * 4;
        *(uint2*)dst = make_uint2(0u, 0u);
        return;
    }
}
#define PREP_N (165888 + 55296 + 14112 + 192 + 288 + 288 + 192 + 192 + 24960)

// ---------------- xTpad interior: coalesced LDS transpose ----------------
__global__ __launch_bounds__(256) void xtpad_kernel(
    const float* __restrict__ x, float* __restrict__ ws)
{
    __shared__ u16 sT[64 * 104];
    u16* bfm = (u16*)(ws + FP32_END);
    const int tid = threadIdx.x;
    const int h = blockIdx.x, b = blockIdx.y;
    const float* xb = x + (((size_t)b * Cc) << 12) + (h << 6);
#pragma unroll
    for (int it = 0; it < 24; ++it) {
        int j = tid + it * 256;            // 0..6143
        int c = j >> 6, p = j & 63;
        sT[p * 104 + c] = f2bf(xb[((size_t)c << 12) + p]);
    }
    __syncthreads();
    u16* dst = bfm + BF_XTPAD + ((size_t)(b * 66 + h + 1) * 66 + 1) * 96;
#pragma unroll
    for (int it = 0; it < 6; ++it) {
        int j = tid + it * 256;            // 0..1535
        int pos = j / 24, c4 = j % 24;
        const u16* s = &sT[pos * 104 + c4 * 4];
        *(uint2*)(dst + pos * 96 + c4 * 4) = make_uint2(
            (unsigned)s[0] | ((unsigned)s[1] << 16),
            (unsigned)s[2] | ((unsigned)s[3] << 16));
    }
}

// ---------------- offset conv v3: 8-wave block, strip loaded once ----------------
__global__ __launch_bounds__(512) void offconv_mfma(
    const float* __restrict__ ws, float* __restrict__ off)
{
    __shared__ u16 sX[3 * 66 * 98];        // [r][col][98-pad ch]
    const u16* bf = (const u16*)(ws + FP32_END);
    const u16* xp = bf + BF_XTPAD;
    const u16* wof = bf + BF_WOF;
    const int tid = threadIdx.x;
    const int lane = tid & 63, wid = tid >> 6;
    const int lane15 = lane & 15, quad = lane >> 4;
    const int h = blockIdx.x;
    const int b = blockIdx.z;
    const int f0 = (wid >> 2) * 6;
    const int pos = (wid & 3) * 16 + lane15;

#pragma unroll
    for (int it = 0; it < 10; ++it) {
        int j = tid + it * 512;            // uint2 chunks: 3*66*24 = 4752
        if (j < 4752) {
            int r = j / (66 * 24);
            int rem = j % (66 * 24);
            int col = rem / 24, c4 = rem % 24;
            uint2 v = *(const uint2*)(xp + ((size_t)((b * 66 + h + r) * 66 + col)) * 96 + c4 * 4);
            *(uint2*)(&sX[(r * 66 + col) * 98 + c4 * 4]) = v;
        }
    }
    __syncthreads();

    f32x4 acc[6];
#pragma unroll
    for (int f = 0; f < 6; ++f) acc[f] = (f32x4){0.f, 0.f, 0.f, 0.f};

#pragma unroll
    for (int tap = 0; tap < 9; ++tap) {
        const int ky = tap / 3, kx = tap % 3;
        const u16* brow = &sX[(ky * 66 + kx + pos) * 98 + quad * 8];
#pragma unroll
        for (int cc = 0; cc < 3; ++cc) {
            s16x8 bb = *(const s16x8*)(brow + cc * 32);
            const int s = tap * 3 + cc;
#pragma unroll
            for (int f = 0; f < 6; ++f) {
                s16x8 a = *(const s16x8*)(wof + ((size_t)((f0 + f) * 27 + s) * 64 + lane) * 8);
                acc[f] = __builtin_amdgcn_mfma_f32_16x16x32_bf16(a, bb, acc[f], 0, 0, 0);
            }
        }
    }

    const float* bcat = ws + OFF_BCAT;
    const int p = (h << 6) + pos;
#pragma unroll
    for (int f = 0; f < 6; ++f) {
        float* dst = off + (((size_t)(b * 192 + (f0 + f) * 16 + quad * 4)) << 12) + p;
#pragma unroll
        for (int r = 0; r < 4; ++r)
            dst[(size_t)r << 12] = acc[f][r] + bcat[(f0 + f) * 16 + quad * 4 + r];
    }
}

// ---------------- deformable sampling v6: shared sWI (single 31.4 KB alloc) ----------------
template<int K>
__device__ __forceinline__ void samp_v6(
    int ksel, float* __restrict__ sWI,
    const float* __restrict__ ws, u16* __restrict__ yt)
{
    constexpr int K2 = K * K;
    constexpr int R = (K - 1) / 2;
    const int tb = (ksel == 0) ? 0 : ((ksel == 1) ? 18 : 68);

    const int tid = threadIdx.x;
    const int b = blockIdx.z;
    const int p0 = blockIdx.x * 20;

    const float* offb = ws + OFF_OFF + ((size_t)(b * 192 + tb)) * HWp;
    for (int i = tid; i < K2 * 20; i += 256) {
        int t = i / 20, q = i % 20;
        int p = min(p0 + q, 4095);
        int hh = p >> 6, wp = p & 63;
        float dy = offb[(size_t)t * HWp + p];
        float dx = offb[(size_t)(K2 + t) * HWp + p];
        int ky = t / K - R, kx = t % K - R;
        float py = fminf(fmaxf((float)(hh + ky) + dy, 0.f), 63.f);
        float px = fminf(fmaxf((float)(wp + kx) + dx, 0.f), 63.f);
        float fy = floorf(py), fx = floorf(px);
        int y0 = (int)fy, x0 = (int)fx;
        float wy = py - fy, wx = px - fx;
        int y1 = min(y0 + 1, 63), x1 = min(x0 + 1, 63);
        float w11 = wy * wx;
        float w10 = wy - w11;
        float w01 = wx - w11;
        float w00 = 1.f - wy - wx + w11;
        float* dst = &sWI[i * 8];
        dst[0] = w00; dst[1] = w01; dst[2] = w10; dst[3] = w11;
        dst[4] = __int_as_float(((y0 + 1) * 66 + x0 + 1) * 96);
        dst[5] = __int_as_float(((y0 + 1) * 66 + x1 + 1) * 96);
        dst[6] = __int_as_float(((y1 + 1) * 66 + x0 + 1) * 96);
        dst[7] = __int_as_float(((y1 + 1) * 66 + x1 + 1) * 96);
    }
    __syncthreads();

    const int c8 = tid % 12;
    const int q  = tid / 12;
    const int p  = p0 + q;
    if (tid < 240 && p < 4096) {           // <-- tail guard restored (bug fix)
        const int c = c8 * 8;

        const u16* xc = (const u16*)(ws + FP32_END) + BF_XTPAD + (size_t)b * 66 * 66 * 96 + c;
        const float* wdT = ws + OFF_WDWT + ksel * 4704 + c;

        float acc[8];
#pragma unroll
        for (int k = 0; k < 8; ++k) acc[k] = 0.f;

        for (int t = 0; t < K2; ++t) {
            const float4 W = *(const float4*)(&sWI[(t * 20 + q) * 8]);
            const float4 I = *(const float4*)(&sWI[(t * 20 + q) * 8 + 4]);
            const uint4 u00 = *(const uint4*)(xc + __float_as_int(I.x));
            const uint4 u01 = *(const uint4*)(xc + __float_as_int(I.y));
            const uint4 u10 = *(const uint4*)(xc + __float_as_int(I.z));
            const uint4 u11 = *(const uint4*)(xc + __float_as_int(I.w));
            const float4 wda = *(const float4*)(wdT + t * 96);
            const float4 wdb = *(const float4*)(wdT + t * 96 + 4);
            const unsigned a00[4] = {u00.x, u00.y, u00.z, u00.w};
            const unsigned a01[4] = {u01.x, u01.y, u01.z, u01.w};
            const unsigned a10[4] = {u10.x, u10.y, u10.z, u10.w};
            const unsigned a11[4] = {u11.x, u11.y, u11.z, u11.w};
            const float wd[8] = {wda.x, wda.y, wda.z, wda.w, wdb.x, wdb.y, wdb.z, wdb.w};
#pragma unroll
            for (int d = 0; d < 4; ++d) {
                float vlo = fmaf(W.x, bflo(a00[d]), fmaf(W.y, bflo(a01[d]),
                            fmaf(W.z, bflo(a10[d]), W.w * bflo(a11[d]))));
                float vhi = fmaf(W.x, bfhi(a00[d]), fmaf(W.y, bfhi(a01[d]),
                            fmaf(W.z, bfhi(a10[d]), W.w * bfhi(a11[d]))));
                acc[2 * d]     = fmaf(wd[2 * d],     vlo, acc[2 * d]);
                acc[2 * d + 1] = fmaf(wd[2 * d + 1], vhi, acc[2 * d + 1]);
            }
        }

        const int cb = ksel * Cc + c;
        const float4 sa = *(const float4*)(ws + OFF_SBR + cb);
        const float4 sb = *(const float4*)(ws + OFF_SBR + cb + 4);
        const float4 ha = *(const float4*)(ws + OFF_HBR + cb);
        const float4 hb = *(const float4*)(ws + OFF_HBR + cb + 4);
        const float ss[8] = {sa.x, sa.y, sa.z, sa.w, sb.x, sb.y, sb.z, sb.w};
        const float hh8[8] = {ha.x, ha.y, ha.z, ha.w, hb.x, hb.y, hb.z, hb.w};
        unsigned r[4];
#pragma unroll
        for (int d = 0; d < 4; ++d) {
            u16 lo = f2bf(fmaxf(fmaf(acc[2 * d],     ss[2 * d],     hh8[2 * d]),     0.f));
            u16 hi = f2bf(fmaxf(fmaf(acc[2 * d + 1], ss[2 * d + 1], hh8[2 * d + 1]), 0.f));
            r[d] = (unsigned)lo | ((unsigned)hi << 16);
        }
        *(uint4*)(yt + ((size_t)(b << 12) + p) * C3 + cb) = make_uint4(r[0], r[1], r[2], r[3]);
    }
}

__global__ __launch_bounds__(256, 4) void sampdw6_kernel(float* __restrict__ ws)
{
    __shared__ float sWI[49 * 20 * 8];     // single allocation, max-K sized
    u16* yt = (u16*)(ws + FP32_END) + BF_YT;
    const int e = blockIdx.y;
    if (e == 0)      samp_v6<3>(0, sWI, ws, yt);
    else if (e == 1) samp_v6<5>(1, sWI, ws, yt);
    else             samp_v6<7>(2, sWI, ws, yt);
}

// ---------------- pointwise v2: 8-wave block, y-tile loaded once ----------------
__global__ __launch_bounds__(512) void pwconv_mfma(
    const float* __restrict__ ws, float* __restrict__ out)
{
    __shared__ u16 sB[64 * 296];
    const u16* bf = (const u16*)(ws + FP32_END);
    const u16* yt = bf + BF_YT;
    const u16* wpw = bf + BF_WPW;
    const int tid = threadIdx.x;
    const int lane = tid & 63, wid = tid >> 6;
    const int lane15 = lane & 15, quad = lane >> 4;
    const int p0 = blockIdx.x * 64;
    const int b = blockIdx.z;
    const int f0 = (wid >> 2) * 6;
    const int pos = (wid & 3) * 16 + lane15;

#pragma unroll
    for (int it = 0; it < 5; ++it) {
        int j = tid + it * 512;            // 0..2303 uint4 chunks
        if (j < 2304) {
            int ps = j / 36, c8 = j % 36;
            *(uint4*)(&sB[ps * 296 + c8 * 8]) =
                *(const uint4*)(yt + ((size_t)(b << 12) + p0 + ps) * C3 + c8 * 8);
        }
    }
    __syncthreads();

    f32x4 acc[6];
#pragma unroll
    for (int f = 0; f < 6; ++f) acc[f] = (f32x4){0.f, 0.f, 0.f, 0.f};

    const u16* brow = &sB[pos * 296 + quad * 8];
#pragma unroll
    for (int s = 0; s < 9; ++s) {
        s16x8 bb = *(const s16x8*)(brow + s * 32);
#pragma unroll
        for (int f = 0; f < 6; ++f) {
            s16x8 a = *(const s16x8*)(wpw + ((size_t)((f0 + f) * 9 + s) * 64 + lane) * 8);
            acc[f] = __builtin_amdgcn_mfma_f32_16x16x32_bf16(a, bb, acc[f], 0, 0, 0);
        }
    }

    const float* spw = ws + OFF_SPW;
    const float* hpw = ws + OFF_HPW;
    const int p = p0 + pos;
#pragma unroll
    for (int f = 0; f < 6; ++f) {
        float* dst = out + (((size_t)(b * Oo + (f0 + f) * 16 + quad * 4)) << 12) + p;
#pragma unroll
        for (int r = 0; r < 4; ++r) {
            int o = (f0 + f) * 16 + quad * 4 + r;
            dst[(size_t)r << 12] = fmaxf(fmaf(acc[f][r], spw[o], hpw[o]), 0.f);
        }
    }
}

extern "C" void kernel_launch(void* const* d_in, const int* in_sizes, int n_in,
                              void* d_out, int out_size, void* d_ws, size_t ws_size,
                              hipStream_t stream)
{
    const float* x     = (const float*)d_in[0];
    const float* w3    = (const float*)d_in[1];
    const float* b3    = (const float*)d_in[2];
    const float* dw3   = (const float*)d_in[3];
    const float* g3    = (const float*)d_in[4];
    const float* be3   = (const float*)d_in[5];
    const float* m3    = (const float*)d_in[6];
    const float* v3    = (const float*)d_in[7];
    const float* w5    = (const float*)d_in[8];
    const float* b5    = (const float*)d_in[9];
    const float* dw5   = (const float*)d_in[10];
    const float* g5    = (const float*)d_in[11];
    const float* be5   = (const float*)d_in[12];
    const float* m5    = (const float*)d_in[13];
    const float* v5    = (const float*)d_in[14];
    const float* w7    = (const float*)d_in[15];
    const float* b7    = (const float*)d_in[16];
    const float* dw7   = (const float*)d_in[17];
    const float* g7    = (const float*)d_in[18];
    const float* be7   = (const float*)d_in[19];
    const float* m7    = (const float*)d_in[20];
    const float* v7    = (const float*)d_in[21];
    const float* wpw   = (const float*)d_in[22];
    const float* gp    = (const float*)d_in[23];
    const float* bp    = (const float*)d_in[24];
    const float* mp    = (const float*)d_in[25];
    const float* vp    = (const float*)d_in[26];

    float* ws = (float*)d_ws;
    float* out = (float*)d_out;

    {   // 1) prep (+ halo zero)
        prep_kernel<<<(PREP_N + 255) / 256, 256, 0, stream>>>(
            w3, b3, dw3, g3, be3, m3, v3,
            w5, b5, dw5, g5, be5, m5, v5,
            w7, b7, dw7, g7, be7, m7, v7,
            wpw, gp, bp, mp, vp, ws);
    }
    {   // 1b) interior transpose
        dim3 grid(64, Bb);
        xtpad_kernel<<<grid, 256, 0, stream>>>(x, ws);
    }
    {   // 2) fused offset conv (8-wave, strip loaded once)
        dim3 grid(64, 1, Bb);
        offconv_mfma<<<grid, 512, 0, stream>>>(ws, ws + OFF_OFF);
    }
    {   // 3) deformable sampling + depthwise + BN + ReLU
        dim3 grid(205, 3, Bb);
        sampdw6_kernel<<<grid, 256, 0, stream>>>(ws);
    }
    {   // 4) pointwise (8-wave) + BN + ReLU
        dim3 grid(64, 1, Bb);
        pwconv_mfma<<<grid, 512, 0, stream>>>(ws, out);
    }
}

// Round 9
// 190.964 us; speedup vs baseline: 3.2829x; 1.0937x over previous
//
#include <hip/hip_runtime.h>
#include <hip/hip_fp16.h>
#include <math.h>

typedef unsigned short u16;
typedef _Float16 f16x8 __attribute__((ext_vector_type(8)));
typedef float f32x4 __attribute__((ext_vector_type(4)));

#define HWp 4096
#define Cc 96
#define Bb 4
#define Oo 192
#define C3 288

// ---------- fp32 workspace region (float offsets) ----------
#define OFF_OFF   0           // [4][192][4096]
#define OFF_WDWT  3145728     // [3][49][96]
#define OFF_BCAT  3159840     // [192]
#define OFF_SBR   3160032     // [288]
#define OFF_HBR   3160320     // [288]
#define OFF_SPW   3160608     // [192]
#define OFF_HPW   3160800     // [192]
#define FP32_END  3160992
// ---------- f16 region (u16 offsets, base = ws + FP32_END) ----------
#define BF_XTPAD  0           // [4][66][66][96]
#define BF_WOF    1672704     // 12 frag x 27 step x 64 lane x 8
#define BF_WPW    1838592     // 12 frag x 9 step x 64 lane x 8
#define BF_YT     1893888     // [4][4096][288]

__device__ __forceinline__ u16 f2h(float f) { return __half_as_ushort(__float2half(f)); }
__device__ __forceinline__ unsigned h2u(__half2 h) { union { __half2 h; unsigned u; } t; t.h = h; return t.u; }
__device__ __forceinline__ __half2 u2h(unsigned u) { union { __half2 h; unsigned u; } t; t.u = u; return t.h; }

#define PREP_N (165888 + 55296 + 14112 + 192 + 288 + 288 + 192 + 192 + 24960)
#define PREP_BLK ((PREP_N + 255) / 256)

// ---------------- prep + xtpad merged ----------------
// blocks 0..255: xtpad LDS transpose; blocks 256..: weight repack / BN fold / halo zero
__global__ __launch_bounds__(256) void prep_kernel(
    const float* __restrict__ x,
    const float* __restrict__ w3, const float* __restrict__ b3, const float* __restrict__ dw3,
    const float* __restrict__ g3, const float* __restrict__ be3, const float* __restrict__ m3, const float* __restrict__ v3,
    const float* __restrict__ w5, const float* __restrict__ b5, const float* __restrict__ dw5,
    const float* __restrict__ g5, const float* __restrict__ be5, const float* __restrict__ m5, const float* __restrict__ v5,
    const float* __restrict__ w7, const float* __restrict__ b7, const float* __restrict__ dw7,
    const float* __restrict__ g7, const float* __restrict__ be7, const float* __restrict__ m7, const float* __restrict__ v7,
    const float* __restrict__ wpw,
    const float* __restrict__ gp, const float* __restrict__ bp, const float* __restrict__ mp, const float* __restrict__ vp,
    float* __restrict__ ws)
{
    __shared__ u16 sT[64 * 104];
    u16* bf = (u16*)(ws + FP32_END);
    const int tid = threadIdx.x;

    if (blockIdx.x < 256) {                 // ---- xtpad interior ----
        const int b = blockIdx.x >> 6, h = blockIdx.x & 63;
        const float* xb = x + (((size_t)b * Cc) << 12) + (h << 6);
#pragma unroll
        for (int it = 0; it < 24; ++it) {
            int j = tid + it * 256;
            int c = j >> 6, p = j & 63;
            sT[p * 104 + c] = f2h(xb[((size_t)c << 12) + p]);
        }
        __syncthreads();
        u16* dst = bf + BF_XTPAD + ((size_t)(b * 66 + h + 1) * 66 + 1) * 96;
#pragma unroll
        for (int it = 0; it < 6; ++it) {
            int j = tid + it * 256;
            int pos = j / 24, c4 = j % 24;
            const u16* s = &sT[pos * 104 + c4 * 4];
            *(uint2*)(dst + pos * 96 + c4 * 4) = make_uint2(
                (unsigned)s[0] | ((unsigned)s[1] << 16),
                (unsigned)s[2] | ((unsigned)s[3] << 16));
        }
        return;
    }

    int i = (blockIdx.x - 256) * 256 + tid;
    if (i < 165888) {                       // WOF frag-linear f16
        int f = i / 13824, r = i % 13824;
        int s = r >> 9, l = r & 511;
        int lane = l >> 3, j = l & 7;
        int o = f * 16 + (lane & 15);
        int k = s * 32 + (lane >> 4) * 8 + j;
        int tap = k / 96, c = k % 96;
        float v = 0.f;
        if (o < 18)       v = w3[o * 864 + c * 9 + tap];
        else if (o < 68)  v = w5[(o - 18) * 864 + c * 9 + tap];
        else if (o < 166) v = w7[(o - 68) * 864 + c * 9 + tap];
        bf[BF_WOF + i] = f2h(v);
        return;
    }
    int j = i - 165888;
    if (j < 55296) {                        // WPW frag-linear f16
        int f = j / 4608, r = j % 4608;
        int s = r >> 9, l = r & 511;
        int lane = l >> 3, jj = l & 7;
        int o = f * 16 + (lane & 15);
        int k = s * 32 + (lane >> 4) * 8 + jj;
        bf[BF_WPW + j] = f2h(wpw[o * C3 + k]);
        return;
    }
    j -= 55296;
    if (j < 14112) {                        // wdwT [3][49][96] fp32
        int ksel = j / 4704, rem = j % 4704;
        int t = rem / 96, c = rem % 96;
        int K2 = (ksel == 0) ? 9 : (ksel == 1) ? 25 : 49;
        const float* dw = (ksel == 0) ? dw3 : (ksel == 1) ? dw5 : dw7;
        ws[OFF_WDWT + j] = (t < K2) ? dw[c * K2 + t] : 0.f;
        return;
    }
    j -= 14112;
    if (j < 192) {                          // bcat
        float v = 0.f;
        if (j < 18)       v = b3[j];
        else if (j < 68)  v = b5[j - 18];
        else if (j < 166) v = b7[j - 68];
        ws[OFF_BCAT + j] = v;
        return;
    }
    j -= 192;
    if (j < C3) {                           // sbr
        int ks = j / Cc, c = j % Cc;
        const float* g = (ks == 0) ? g3 : (ks == 1) ? g5 : g7;
        const float* v = (ks == 0) ? v3 : (ks == 1) ? v5 : v7;
        ws[OFF_SBR + j] = g[c] / sqrtf(v[c] + 1e-5f);
        return;
    }
    j -= C3;
    if (j < C3) {                           // hbr
        int ks = j / Cc, c = j % Cc;
        const float* g = (ks == 0) ? g3 : (ks == 1) ? g5 : g7;
        const float* v = (ks == 0) ? v3 : (ks == 1) ? v5 : v7;
        const float* be = (ks == 0) ? be3 : (ks == 1) ? be5 : be7;
        const float* m = (ks == 0) ? m3 : (ks == 1) ? m5 : m7;
        float inv = g[c] / sqrtf(v[c] + 1e-5f);
        ws[OFF_HBR + j] = be[c] - m[c] * inv;
        return;
    }
    j -= C3;
    if (j < Oo) { ws[OFF_SPW + j] = gp[j] / sqrtf(vp[j] + 1e-5f); return; }
    j -= Oo;
    if (j < Oo) {
        float inv = gp[j] / sqrtf(vp[j] + 1e-5f);
        ws[OFF_HPW + j] = bp[j] - mp[j] * inv;
        return;
    }
    j -= Oo;
    if (j < 24960) {                        // halo zero
        int c4 = j % 24, rem = j / 24;
        int cell = rem % 260, bb = rem / 260;
        int row, col;
        if (cell < 66)       { row = 0;  col = cell; }
        else if (cell < 132) { row = 65; col = cell - 66; }
        else if (cell < 196) { row = cell - 132 + 1; col = 0; }
        else                 { row = cell - 196 + 1; col = 65; }
        u16* dst = bf + BF_XTPAD + ((size_t)(bb * 66 + row) * 66 + col) * 96 + c4 * 4;
        *(uint2*)dst = make_uint2(0u, 0u);
        return;
    }
}

// ---------------- offset conv: 8-wave block, f16 MFMA, strip loaded once ----------------
__global__ __launch_bounds__(512) void offconv_mfma(
    const float* __restrict__ ws, float* __restrict__ off)
{
    __shared__ u16 sX[3 * 66 * 98];
    const u16* bf = (const u16*)(ws + FP32_END);
    const u16* xp = bf + BF_XTPAD;
    const u16* wof = bf + BF_WOF;
    const int tid = threadIdx.x;
    const int lane = tid & 63, wid = tid >> 6;
    const int lane15 = lane & 15, quad = lane >> 4;
    const int h = blockIdx.x;
    const int b = blockIdx.z;
    const int f0 = (wid >> 2) * 6;
    const int pos = (wid & 3) * 16 + lane15;

#pragma unroll
    for (int it = 0; it < 10; ++it) {
        int j = tid + it * 512;
        if (j < 4752) {
            int r = j / (66 * 24);
            int rem = j % (66 * 24);
            int col = rem / 24, c4 = rem % 24;
            uint2 v = *(const uint2*)(xp + ((size_t)((b * 66 + h + r) * 66 + col)) * 96 + c4 * 4);
            *(uint2*)(&sX[(r * 66 + col) * 98 + c4 * 4]) = v;
        }
    }
    __syncthreads();

    f32x4 acc[6];
#pragma unroll
    for (int f = 0; f < 6; ++f) acc[f] = (f32x4){0.f, 0.f, 0.f, 0.f};

#pragma unroll
    for (int tap = 0; tap < 9; ++tap) {
        const int ky = tap / 3, kx = tap % 3;
        const u16* brow = &sX[(ky * 66 + kx + pos) * 98 + quad * 8];
#pragma unroll
        for (int cc = 0; cc < 3; ++cc) {
            f16x8 bb = *(const f16x8*)(brow + cc * 32);
            const int s = tap * 3 + cc;
#pragma unroll
            for (int f = 0; f < 6; ++f) {
                f16x8 a = *(const f16x8*)(wof + ((size_t)((f0 + f) * 27 + s) * 64 + lane) * 8);
                acc[f] = __builtin_amdgcn_mfma_f32_16x16x32_f16(a, bb, acc[f], 0, 0, 0);
            }
        }
    }

    const float* bcat = ws + OFF_BCAT;
    const int p = (h << 6) + pos;
#pragma unroll
    for (int f = 0; f < 6; ++f) {
        float* dst = off + (((size_t)(b * 192 + (f0 + f) * 16 + quad * 4)) << 12) + p;
#pragma unroll
        for (int r = 0; r < 4; ++r)
            dst[(size_t)r << 12] = acc[f][r] + bcat[(f0 + f) * 16 + quad * 4 + r];
    }
}

// ---------------- deformable sampling v7: packed-f16 interp, 16B LDS entry, balanced grid ----------------
template<int K>
__device__ __forceinline__ void samp_v7(
    int ksel, int p0, int rounds, uint4* __restrict__ sWI,
    const float* __restrict__ ws, u16* __restrict__ yt)
{
    constexpr int K2 = K * K;
    constexpr int R = (K - 1) / 2;
    const int tb = (ksel == 0) ? 0 : ((ksel == 1) ? 18 : 68);

    const int tid = threadIdx.x;
    const int b = blockIdx.z;
    const float* offb = ws + OFF_OFF + ((size_t)(b * 192 + tb)) * HWp;
    const int c8 = tid % 12;
    const int q  = tid / 12;
    const int c = c8 * 8;
    const u16* xh = (const u16*)(ws + FP32_END) + BF_XTPAD + (size_t)b * 66 * 66 * 96;
    const char* xcb = (const char*)xh + c * 2;
    const float* wdT = ws + OFF_WDWT + ksel * 4704 + c;

    for (int r = 0; r < rounds; ++r) {
        const int p0r = p0 + r * 20;
        // phase 1: bilinear weights + packed corner offsets
        for (int i = tid; i < K2 * 20; i += 256) {
            int t = i / 20, qq = i % 20;
            int p = min(p0r + qq, 4095);
            int hh = p >> 6, wp = p & 63;
            float dy = offb[(size_t)t * HWp + p];
            float dx = offb[(size_t)(K2 + t) * HWp + p];
            int ky = t / K - R, kx = t % K - R;
            float py = fminf(fmaxf((float)(hh + ky) + dy, 0.f), 63.f);
            float px = fminf(fmaxf((float)(wp + kx) + dx, 0.f), 63.f);
            float fy = floorf(py), fx = floorf(px);
            int y0 = (int)fy, x0 = (int)fx;
            float wy = py - fy, wx = px - fx;
            int y1 = min(y0 + 1, 63), x1 = min(x0 + 1, 63);
            float w11 = wy * wx;
            float w10 = wy - w11;
            float w01 = wx - w11;
            float w00 = 1.f - wy - wx + w11;
            unsigned wA = h2u(__floats2half2_rn(w00, w01));
            unsigned wB = h2u(__floats2half2_rn(w10, w11));
            unsigned o00 = (unsigned)((y0 + 1) * 66 + (x0 + 1)) * 192u;   // byte offset
            unsigned d01 = (unsigned)(x1 - x0) * 192u;                    // 0 or 192
            unsigned d10 = (unsigned)(y1 - y0) * 12672u;                  // 0 or 66*192
            sWI[i] = make_uint4(wA, wB, o00, d01 | (d10 << 16));
        }
        __syncthreads();

        const int p = p0r + q;
        if (tid < 240 && p < 4096) {
            float acc[8];
#pragma unroll
            for (int k = 0; k < 8; ++k) acc[k] = 0.f;

            for (int t = 0; t < K2; ++t) {
                const uint4 e = sWI[t * 20 + q];
                const __half2 wA = u2h(e.x), wB = u2h(e.y);
                const __half2 w00b = __low2half2(wA), w01b = __high2half2(wA);
                const __half2 w10b = __low2half2(wB), w11b = __high2half2(wB);
                const unsigned d01 = e.w & 0xffffu, d10 = e.w >> 16;
                const uint4 u00 = *(const uint4*)(xcb + e.z);
                const uint4 u01 = *(const uint4*)(xcb + e.z + d01);
                const uint4 u10 = *(const uint4*)(xcb + e.z + d10);
                const uint4 u11 = *(const uint4*)(xcb + e.z + d10 + d01);
                const float4 wda = *(const float4*)(wdT + t * 96);
                const float4 wdb = *(const float4*)(wdT + t * 96 + 4);
                const unsigned a00[4] = {u00.x, u00.y, u00.z, u00.w};
                const unsigned a01[4] = {u01.x, u01.y, u01.z, u01.w};
                const unsigned a10[4] = {u10.x, u10.y, u10.z, u10.w};
                const unsigned a11[4] = {u11.x, u11.y, u11.z, u11.w};
                const float wd[8] = {wda.x, wda.y, wda.z, wda.w, wdb.x, wdb.y, wdb.z, wdb.w};
#pragma unroll
                for (int d = 0; d < 4; ++d) {
                    __half2 v = __hmul2(w00b, u2h(a00[d]));
                    v = __hfma2(w01b, u2h(a01[d]), v);
                    v = __hfma2(w10b, u2h(a10[d]), v);
                    v = __hfma2(w11b, u2h(a11[d]), v);
                    acc[2 * d]     = fmaf(wd[2 * d],     __low2float(v),  acc[2 * d]);
                    acc[2 * d + 1] = fmaf(wd[2 * d + 1], __high2float(v), acc[2 * d + 1]);
                }
            }

            const int cb = ksel * Cc + c;
            const float4 sa = *(const float4*)(ws + OFF_SBR + cb);
            const float4 sb = *(const float4*)(ws + OFF_SBR + cb + 4);
            const float4 ha = *(const float4*)(ws + OFF_HBR + cb);
            const float4 hb = *(const float4*)(ws + OFF_HBR + cb + 4);
            const float ss[8] = {sa.x, sa.y, sa.z, sa.w, sb.x, sb.y, sb.z, sb.w};
            const float hh8[8] = {ha.x, ha.y, ha.z, ha.w, hb.x, hb.y, hb.z, hb.w};
            unsigned rr[4];
#pragma unroll
            for (int d = 0; d < 4; ++d) {
                float lo = fmaxf(fmaf(acc[2 * d],     ss[2 * d],     hh8[2 * d]),     0.f);
                float hi = fmaxf(fmaf(acc[2 * d + 1], ss[2 * d + 1], hh8[2 * d + 1]), 0.f);
                rr[d] = h2u(__floats2half2_rn(lo, hi));
            }
            *(uint4*)(yt + ((size_t)(b << 12) + p) * C3 + cb) = make_uint4(rr[0], rr[1], rr[2], rr[3]);
        }
        if (r + 1 < rounds) __syncthreads();
    }
}

__global__ __launch_bounds__(256, 6) void sampdw7_kernel(float* __restrict__ ws)
{
    __shared__ uint4 sWI[980];             // 15.7 KB
    u16* yt = (u16*)(ws + FP32_END) + BF_YT;
    const int bx = blockIdx.x;
    if (bx < 41)        samp_v7<3>(0, bx * 100, 5, sWI, ws, yt);
    else if (bx < 144)  samp_v7<5>(1, (bx - 41) * 40, 2, sWI, ws, yt);
    else                samp_v7<7>(2, (bx - 144) * 20, 1, sWI, ws, yt);
}

// ---------------- pointwise: 8-wave block, f16 MFMA + BN + ReLU ----------------
__global__ __launch_bounds__(512) void pwconv_mfma(
    const float* __restrict__ ws, float* __restrict__ out)
{
    __shared__ u16 sB[64 * 296];
    const u16* bf = (const u16*)(ws + FP32_END);
    const u16* yt = bf + BF_YT;
    const u16* wpw = bf + BF_WPW;
    const int tid = threadIdx.x;
    const int lane = tid & 63, wid = tid >> 6;
    const int lane15 = lane & 15, quad = lane >> 4;
    const int p0 = blockIdx.x * 64;
    const int b = blockIdx.z;
    const int f0 = (wid >> 2) * 6;
    const int pos = (wid & 3) * 16 + lane15;

#pragma unroll
    for (int it = 0; it < 5; ++it) {
        int j = tid + it * 512;
        if (j < 2304) {
            int ps = j / 36, c8 = j % 36;
            *(uint4*)(&sB[ps * 296 + c8 * 8]) =
                *(const uint4*)(yt + ((size_t)(b << 12) + p0 + ps) * C3 + c8 * 8);
        }
    }
    __syncthreads();

    f32x4 acc[6];
#pragma unroll
    for (int f = 0; f < 6; ++f) acc[f] = (f32x4){0.f, 0.f, 0.f, 0.f};

    const u16* brow = &sB[pos * 296 + quad * 8];
#pragma unroll
    for (int s = 0; s < 9; ++s) {
        f16x8 bb = *(const f16x8*)(brow + s * 32);
#pragma unroll
        for (int f = 0; f < 6; ++f) {
            f16x8 a = *(const f16x8*)(wpw + ((size_t)((f0 + f) * 9 + s) * 64 + lane) * 8);
            acc[f] = __builtin_amdgcn_mfma_f32_16x16x32_f16(a, bb, acc[f], 0, 0, 0);
        }
    }

    const float* spw = ws + OFF_SPW;
    const float* hpw = ws + OFF_HPW;
    const int p = p0 + pos;
#pragma unroll
    for (int f = 0; f < 6; ++f) {
        float* dst = out + (((size_t)(b * Oo + (f0 + f) * 16 + quad * 4)) << 12) + p;
#pragma unroll
        for (int r = 0; r < 4; ++r) {
            int o = (f0 + f) * 16 + quad * 4 + r;
            dst[(size_t)r << 12] = fmaxf(fmaf(acc[f][r], spw[o], hpw[o]), 0.f);
        }
    }
}

extern "C" void kernel_launch(void* const* d_in, const int* in_sizes, int n_in,
                              void* d_out, int out_size, void* d_ws, size_t ws_size,
                              hipStream_t stream)
{
    const float* x     = (const float*)d_in[0];
    const float* w3    = (const float*)d_in[1];
    const float* b3    = (const float*)d_in[2];
    const float* dw3   = (const float*)d_in[3];
    const float* g3    = (const float*)d_in[4];
    const float* be3   = (const float*)d_in[5];
    const float* m3    = (const float*)d_in[6];
    const float* v3    = (const float*)d_in[7];
    const float* w5    = (const float*)d_in[8];
    const float* b5    = (const float*)d_in[9];
    const float* dw5   = (const float*)d_in[10];
    const float* g5    = (const float*)d_in[11];
    const float* be5   = (const float*)d_in[12];
    const float* m5    = (const float*)d_in[13];
    const float* v5    = (const float*)d_in[14];
    const float* w7    = (const float*)d_in[15];
    const float* b7    = (const float*)d_in[16];
    const float* dw7   = (const float*)d_in[17];
    const float* g7    = (const float*)d_in[18];
    const float* be7   = (const float*)d_in[19];
    const float* m7    = (const float*)d_in[20];
    const float* v7    = (const float*)d_in[21];
    const float* wpw   = (const float*)d_in[22];
    const float* gp    = (const float*)d_in[23];
    const float* bp    = (const float*)d_in[24];
    const float* mp    = (const float*)d_in[25];
    const float* vp    = (const float*)d_in[26];

    float* ws = (float*)d_ws;
    float* out = (float*)d_out;

    {   // 1) prep + xtpad (merged)
        prep_kernel<<<256 + PREP_BLK, 256, 0, stream>>>(
            x,
            w3, b3, dw3, g3, be3, m3, v3,
            w5, b5, dw5, g5, be5, m5, v5,
            w7, b7, dw7, g7, be7, m7, v7,
            wpw, gp, bp, mp, vp, ws);
    }
    {   // 2) fused offset conv
        dim3 grid(64, 1, Bb);
        offconv_mfma<<<grid, 512, 0, stream>>>(ws, ws + OFF_OFF);
    }
    {   // 3) deformable sampling + depthwise + BN + ReLU (balanced grid)
        dim3 grid(349, 1, Bb);
        sampdw7_kernel<<<grid, 256, 0, stream>>>(ws);
    }
    {   // 4) pointwise + BN + ReLU
        dim3 grid(64, 1, Bb);
        pwconv_mfma<<<grid, 512, 0, stream>>>(ws, out);
    }
}

// Round 10
// 176.873 us; speedup vs baseline: 3.5445x; 1.0797x over previous
//
#include <hip/hip_runtime.h>
#include <hip/hip_fp16.h>
#include <math.h>

typedef unsigned short u16;
typedef _Float16 f16x8 __attribute__((ext_vector_type(8)));
typedef float f32x4 __attribute__((ext_vector_type(4)));

#define HWp 4096
#define Cc 96
#define Bb 4
#define Oo 192
#define C3 288

// ---------- fp32 workspace region (float offsets) ----------
#define OFF_WDWT  0           // [3][49][96]
#define OFF_BCAT  14112       // [192]
#define OFF_SBR   14304       // [288]
#define OFF_HBR   14592       // [288]
#define OFF_SPW   14880       // [192]
#define OFF_HPW   15072       // [192]
#define FP32_END  15264
// ---------- f16 region (u16 offsets, base = ws + FP32_END) ----------
#define BF_XTPAD  0           // [4][66][66][96]
#define BF_WOF    1672704     // 12 frag x 27 step x 64 lane x 8
#define BF_WPW    1838592     // 12 frag x 9 step x 64 lane x 8

__device__ __forceinline__ u16 f2h(float f) { return __half_as_ushort(__float2half(f)); }
__device__ __forceinline__ unsigned h2u(__half2 h) { union { __half2 h; unsigned u; } t; t.h = h; return t.u; }
__device__ __forceinline__ __half2 u2h(unsigned u) { union { __half2 h; unsigned u; } t; t.u = u; return t.h; }

#define PREP_N (165888 + 55296 + 14112 + 192 + 288 + 288 + 192 + 192 + 24960)
#define PREP_BLK ((PREP_N + 255) / 256)

// ---------------- prep + xtpad merged ----------------
__global__ __launch_bounds__(256) void prep_kernel(
    const float* __restrict__ x,
    const float* __restrict__ w3, const float* __restrict__ b3, const float* __restrict__ dw3,
    const float* __restrict__ g3, const float* __restrict__ be3, const float* __restrict__ m3, const float* __restrict__ v3,
    const float* __restrict__ w5, const float* __restrict__ b5, const float* __restrict__ dw5,
    const float* __restrict__ g5, const float* __restrict__ be5, const float* __restrict__ m5, const float* __restrict__ v5,
    const float* __restrict__ w7, const float* __restrict__ b7, const float* __restrict__ dw7,
    const float* __restrict__ g7, const float* __restrict__ be7, const float* __restrict__ m7, const float* __restrict__ v7,
    const float* __restrict__ wpw,
    const float* __restrict__ gp, const float* __restrict__ bp, const float* __restrict__ mp, const float* __restrict__ vp,
    float* __restrict__ ws)
{
    __shared__ u16 sT[64 * 104];
    u16* bf = (u16*)(ws + FP32_END);
    const int tid = threadIdx.x;

    if (blockIdx.x < 256) {                 // ---- xtpad interior ----
        const int b = blockIdx.x >> 6, h = blockIdx.x & 63;
        const float* xb = x + (((size_t)b * Cc) << 12) + (h << 6);
#pragma unroll
        for (int it = 0; it < 24; ++it) {
            int j = tid + it * 256;
            int c = j >> 6, p = j & 63;
            sT[p * 104 + c] = f2h(xb[((size_t)c << 12) + p]);
        }
        __syncthreads();
        u16* dst = bf + BF_XTPAD + ((size_t)(b * 66 + h + 1) * 66 + 1) * 96;
#pragma unroll
        for (int it = 0; it < 6; ++it) {
            int j = tid + it * 256;
            int pos = j / 24, c4 = j % 24;
            const u16* s = &sT[pos * 104 + c4 * 4];
            *(uint2*)(dst + pos * 96 + c4 * 4) = make_uint2(
                (unsigned)s[0] | ((unsigned)s[1] << 16),
                (unsigned)s[2] | ((unsigned)s[3] << 16));
        }
        return;
    }

    int i = (blockIdx.x - 256) * 256 + tid;
    if (i < 165888) {                       // WOF frag-linear f16
        int f = i / 13824, r = i % 13824;
        int s = r >> 9, l = r & 511;
        int lane = l >> 3, j = l & 7;
        int o = f * 16 + (lane & 15);
        int k = s * 32 + (lane >> 4) * 8 + j;
        int tap = k / 96, c = k % 96;
        float v = 0.f;
        if (o < 18)       v = w3[o * 864 + c * 9 + tap];
        else if (o < 68)  v = w5[(o - 18) * 864 + c * 9 + tap];
        else if (o < 166) v = w7[(o - 68) * 864 + c * 9 + tap];
        bf[BF_WOF + i] = f2h(v);
        return;
    }
    int j = i - 165888;
    if (j < 55296) {                        // WPW frag-linear f16
        int f = j / 4608, r = j % 4608;
        int s = r >> 9, l = r & 511;
        int lane = l >> 3, jj = l & 7;
        int o = f * 16 + (lane & 15);
        int k = s * 32 + (lane >> 4) * 8 + jj;
        bf[BF_WPW + j] = f2h(wpw[o * C3 + k]);
        return;
    }
    j -= 55296;
    if (j < 14112) {                        // wdwT [3][49][96] fp32
        int ksel = j / 4704, rem = j % 4704;
        int t = rem / 96, c = rem % 96;
        int K2 = (ksel == 0) ? 9 : (ksel == 1) ? 25 : 49;
        const float* dw = (ksel == 0) ? dw3 : (ksel == 1) ? dw5 : dw7;
        ws[OFF_WDWT + j] = (t < K2) ? dw[c * K2 + t] : 0.f;
        return;
    }
    j -= 14112;
    if (j < 192) {                          // bcat
        float v = 0.f;
        if (j < 18)       v = b3[j];
        else if (j < 68)  v = b5[j - 18];
        else if (j < 166) v = b7[j - 68];
        ws[OFF_BCAT + j] = v;
        return;
    }
    j -= 192;
    if (j < C3) {                           // sbr
        int ks = j / Cc, c = j % Cc;
        const float* g = (ks == 0) ? g3 : (ks == 1) ? g5 : g7;
        const float* v = (ks == 0) ? v3 : (ks == 1) ? v5 : v7;
        ws[OFF_SBR + j] = g[c] / sqrtf(v[c] + 1e-5f);
        return;
    }
    j -= C3;
    if (j < C3) {                           // hbr
        int ks = j / Cc, c = j % Cc;
        const float* g = (ks == 0) ? g3 : (ks == 1) ? g5 : g7;
        const float* v = (ks == 0) ? v3 : (ks == 1) ? v5 : v7;
        const float* be = (ks == 0) ? be3 : (ks == 1) ? be5 : be7;
        const float* m = (ks == 0) ? m3 : (ks == 1) ? m5 : m7;
        float inv = g[c] / sqrtf(v[c] + 1e-5f);
        ws[OFF_HBR + j] = be[c] - m[c] * inv;
        return;
    }
    j -= C3;
    if (j < Oo) { ws[OFF_SPW + j] = gp[j] / sqrtf(vp[j] + 1e-5f); return; }
    j -= Oo;
    if (j < Oo) {
        float inv = gp[j] / sqrtf(vp[j] + 1e-5f);
        ws[OFF_HPW + j] = bp[j] - mp[j] * inv;
        return;
    }
    j -= Oo;
    if (j < 24960) {                        // halo zero
        int c4 = j % 24, rem = j / 24;
        int cell = rem % 260, bb = rem / 260;
        int row, col;
        if (cell < 66)       { row = 0;  col = cell; }
        else if (cell < 132) { row = 65; col = cell - 66; }
        else if (cell < 196) { row = cell - 132 + 1; col = 0; }
        else                 { row = cell - 196 + 1; col = 65; }
        u16* dst = bf + BF_XTPAD + ((size_t)(bb * 66 + row) * 66 + col) * 96 + c4 * 4;
        *(uint2*)dst = make_uint2(0u, 0u);
        return;
    }
}

// ---------------- mega kernel: offconv -> sampling -> depthwise -> pwconv, fully fused ----------------
// block = 16 positions (quarter image row), 256 threads (4 waves)
// LDS: regA = sX patch (3x18x104 u16) then sWI (83x16 uint4); regB = soff (192x16 f32) then ytile (16x296 u16)
__global__ __launch_bounds__(256, 4) void mega_kernel(
    const float* __restrict__ ws, float* __restrict__ out)
{
    __shared__ uint4 regA[1328];           // 21248 B
    __shared__ float regB[3072];           // 12288 B
    u16* sX = (u16*)regA;
    uint4* sWI = regA;
    float* soff = regB;
    u16* ytile = (u16*)regB;

    const u16* bf = (const u16*)(ws + FP32_END);
    const u16* xp = bf + BF_XTPAD;
    const int tid = threadIdx.x;
    const int lane = tid & 63, wid = tid >> 6;
    const int lane15 = lane & 15, quad = lane >> 4;
    const int b = blockIdx.z;
    const int p0 = blockIdx.x * 16;
    const int h = p0 >> 6;                 // image row (fixed per block)
    const int w0 = p0 & 63;                // start col (0/16/32/48)

    // ---- phase 1: load 3-row x 18-col patch into sX ----
    {
        const u16* src = xp + ((size_t)(b * 66 + h) * 66 + w0) * 96;
        for (int j = tid; j < 1296; j += 256) {       // 3*18*24 uint2 chunks
            int r = j / 432;
            int rem = j % 432;
            int col = rem / 24, c4 = rem % 24;
            uint2 v = *(const uint2*)(src + ((size_t)(r * 66 + col)) * 96 + c4 * 4);
            *(uint2*)(&sX[(r * 18 + col) * 104 + c4 * 4]) = v;
        }
    }
    __syncthreads();

    // ---- phase 2: offset conv MFMA (M=192 as 12 frags / 4 waves, N=16, K=864) ----
    {
        const u16* wof = bf + BF_WOF;
        f32x4 acc[3];
#pragma unroll
        for (int ff = 0; ff < 3; ++ff) acc[ff] = (f32x4){0.f, 0.f, 0.f, 0.f};
#pragma unroll
        for (int tap = 0; tap < 9; ++tap) {
            const int ky2 = tap / 3, kx2 = tap % 3;
            const u16* brow = &sX[(ky2 * 18 + kx2 + lane15) * 104 + quad * 8];
#pragma unroll
            for (int cc = 0; cc < 3; ++cc) {
                f16x8 bb = *(const f16x8*)(brow + cc * 32);
                const int s = tap * 3 + cc;
#pragma unroll
                for (int ff = 0; ff < 3; ++ff) {
                    const int f = wid * 3 + ff;
                    f16x8 a = *(const f16x8*)(wof + ((size_t)(f * 27 + s) * 64 + lane) * 8);
                    acc[ff] = __builtin_amdgcn_mfma_f32_16x16x32_f16(a, bb, acc[ff], 0, 0, 0);
                }
            }
        }
        const float* bcat = ws + OFF_BCAT;
#pragma unroll
        for (int ff = 0; ff < 3; ++ff) {
#pragma unroll
            for (int r = 0; r < 4; ++r) {
                int co = (wid * 3 + ff) * 16 + quad * 4 + r;
                soff[co * 16 + lane15] = acc[ff][r] + bcat[co];
            }
        }
    }
    __syncthreads();   // sX reads done; soff complete

    // ---- phase 3: bilinear weight/index table (83 taps x 16 pos) -> sWI (clobbers sX) ----
    for (int i = tid; i < 1328; i += 256) {
        int gt = i >> 4, q = i & 15;
        int K, K2, R, tb, t;
        if (gt < 9)       { K = 3; K2 = 9;  R = 1; tb = 0;  t = gt; }
        else if (gt < 34) { K = 5; K2 = 25; R = 2; tb = 18; t = gt - 9; }
        else              { K = 7; K2 = 49; R = 3; tb = 68; t = gt - 34; }
        int ky = t / K - R, kx = t % K - R;
        float dy = soff[(tb + t) * 16 + q];
        float dx = soff[(tb + K2 + t) * 16 + q];
        float py = fminf(fmaxf((float)(h + ky) + dy, 0.f), 63.f);
        float px = fminf(fmaxf((float)(w0 + q + kx) + dx, 0.f), 63.f);
        float fy = floorf(py), fx = floorf(px);
        int y0 = (int)fy, x0 = (int)fx;
        float wy = py - fy, wx = px - fx;
        int y1 = min(y0 + 1, 63), x1 = min(x0 + 1, 63);
        float w11 = wy * wx;
        float w10 = wy - w11;
        float w01 = wx - w11;
        float w00 = 1.f - wy - wx + w11;
        unsigned wA = h2u(__floats2half2_rn(w00, w01));
        unsigned wB = h2u(__floats2half2_rn(w10, w11));
        unsigned o00 = (unsigned)((y0 + 1) * 66 + (x0 + 1)) * 192u;   // byte offset
        unsigned d01 = (unsigned)(x1 - x0) * 192u;
        unsigned d10 = (unsigned)(y1 - y0) * 12672u;
        sWI[i] = make_uint4(wA, wB, o00, d01 | (d10 << 16));
    }
    __syncthreads();   // soff consumed; sWI ready

    // ---- phase 4: gather + depthwise + BN + ReLU -> ytile (clobbers soff) ----
    if (tid < 192) {
        const int c8 = tid % 12;
        const int q  = tid / 12;            // 0..15
        const int c = c8 * 8;
        const u16* xh = xp + (size_t)b * 66 * 66 * 96;
        const char* xcb = (const char*)xh + c * 2;

#pragma unroll
        for (int seg = 0; seg < 3; ++seg) {
            const int g0 = (seg == 0) ? 0 : (seg == 1) ? 9 : 34;
            const int g1 = (seg == 0) ? 9 : (seg == 1) ? 34 : 83;
            const float* wdT = ws + OFF_WDWT + seg * 4704 + c;
            float acc[8];
#pragma unroll
            for (int k = 0; k < 8; ++k) acc[k] = 0.f;

            for (int gt = g0; gt < g1; ++gt) {
                const uint4 e = sWI[(gt << 4) + q];
                const __half2 wAh = u2h(e.x), wBh = u2h(e.y);
                const __half2 w00b = __low2half2(wAh), w01b = __high2half2(wAh);
                const __half2 w10b = __low2half2(wBh), w11b = __high2half2(wBh);
                const unsigned d01 = e.w & 0xffffu, d10 = e.w >> 16;
                const uint4 u00 = *(const uint4*)(xcb + e.z);
                const uint4 u01 = *(const uint4*)(xcb + e.z + d01);
                const uint4 u10 = *(const uint4*)(xcb + e.z + d10);
                const uint4 u11 = *(const uint4*)(xcb + e.z + d10 + d01);
                const float4 wda = *(const float4*)(wdT + (gt - g0) * 96);
                const float4 wdb = *(const float4*)(wdT + (gt - g0) * 96 + 4);
                const unsigned a00[4] = {u00.x, u00.y, u00.z, u00.w};
                const unsigned a01[4] = {u01.x, u01.y, u01.z, u01.w};
                const unsigned a10[4] = {u10.x, u10.y, u10.z, u10.w};
                const unsigned a11[4] = {u11.x, u11.y, u11.z, u11.w};
                const float wd[8] = {wda.x, wda.y, wda.z, wda.w, wdb.x, wdb.y, wdb.z, wdb.w};
#pragma unroll
                for (int d = 0; d < 4; ++d) {
                    __half2 v = __hmul2(w00b, u2h(a00[d]));
                    v = __hfma2(w01b, u2h(a01[d]), v);
                    v = __hfma2(w10b, u2h(a10[d]), v);
                    v = __hfma2(w11b, u2h(a11[d]), v);
                    acc[2 * d]     = fmaf(wd[2 * d],     __low2float(v),  acc[2 * d]);
                    acc[2 * d + 1] = fmaf(wd[2 * d + 1], __high2float(v), acc[2 * d + 1]);
                }
            }

            const int cb = seg * Cc + c;
            const float4 sa = *(const float4*)(ws + OFF_SBR + cb);
            const float4 sb = *(const float4*)(ws + OFF_SBR + cb + 4);
            const float4 ha = *(const float4*)(ws + OFF_HBR + cb);
            const float4 hb = *(const float4*)(ws + OFF_HBR + cb + 4);
            const float ss[8] = {sa.x, sa.y, sa.z, sa.w, sb.x, sb.y, sb.z, sb.w};
            const float hh8[8] = {ha.x, ha.y, ha.z, ha.w, hb.x, hb.y, hb.z, hb.w};
            unsigned rr[4];
#pragma unroll
            for (int d = 0; d < 4; ++d) {
                float lo = fmaxf(fmaf(acc[2 * d],     ss[2 * d],     hh8[2 * d]),     0.f);
                float hi = fmaxf(fmaf(acc[2 * d + 1], ss[2 * d + 1], hh8[2 * d + 1]), 0.f);
                rr[d] = h2u(__floats2half2_rn(lo, hi));
            }
            *(uint4*)(ytile + q * 296 + cb) = make_uint4(rr[0], rr[1], rr[2], rr[3]);
        }
    }
    __syncthreads();   // sWI consumed; ytile ready

    // ---- phase 5: pointwise MFMA (M=192 as 12 frags / 4 waves, N=16, K=288) + BN + ReLU ----
    {
        const u16* wpw = bf + BF_WPW;
        f32x4 acc[3];
#pragma unroll
        for (int ff = 0; ff < 3; ++ff) acc[ff] = (f32x4){0.f, 0.f, 0.f, 0.f};
        const u16* brow = &ytile[lane15 * 296 + quad * 8];
#pragma unroll
        for (int s = 0; s < 9; ++s) {
            f16x8 bb = *(const f16x8*)(brow + s * 32);
#pragma unroll
            for (int ff = 0; ff < 3; ++ff) {
                const int f = wid * 3 + ff;
                f16x8 a = *(const f16x8*)(wpw + ((size_t)(f * 9 + s) * 64 + lane) * 8);
                acc[ff] = __builtin_amdgcn_mfma_f32_16x16x32_f16(a, bb, acc[ff], 0, 0, 0);
            }
        }
        const float* spw = ws + OFF_SPW;
        const float* hpw = ws + OFF_HPW;
        const int p = p0 + lane15;
#pragma unroll
        for (int ff = 0; ff < 3; ++ff) {
#pragma unroll
            for (int r = 0; r < 4; ++r) {
                int o = (wid * 3 + ff) * 16 + quad * 4 + r;
                out[(((size_t)(b * Oo + o)) << 12) + p] =
                    fmaxf(fmaf(acc[ff][r], spw[o], hpw[o]), 0.f);
            }
        }
    }
}

extern "C" void kernel_launch(void* const* d_in, const int* in_sizes, int n_in,
                              void* d_out, int out_size, void* d_ws, size_t ws_size,
                              hipStream_t stream)
{
    const float* x     = (const float*)d_in[0];
    const float* w3    = (const float*)d_in[1];
    const float* b3    = (const float*)d_in[2];
    const float* dw3   = (const float*)d_in[3];
    const float* g3    = (const float*)d_in[4];
    const float* be3   = (const float*)d_in[5];
    const float* m3    = (const float*)d_in[6];
    const float* v3    = (const float*)d_in[7];
    const float* w5    = (const float*)d_in[8];
    const float* b5    = (const float*)d_in[9];
    const float* dw5   = (const float*)d_in[10];
    const float* g5    = (const float*)d_in[11];
    const float* be5   = (const float*)d_in[12];
    const float* m5    = (const float*)d_in[13];
    const float* v5    = (const float*)d_in[14];
    const float* w7    = (const float*)d_in[15];
    const float* b7    = (const float*)d_in[16];
    const float* dw7   = (const float*)d_in[17];
    const float* g7    = (const float*)d_in[18];
    const float* be7   = (const float*)d_in[19];
    const float* m7    = (const float*)d_in[20];
    const float* v7    = (const float*)d_in[21];
    const float* wpw   = (const float*)d_in[22];
    const float* gp    = (const float*)d_in[23];
    const float* bp    = (const float*)d_in[24];
    const float* mp    = (const float*)d_in[25];
    const float* vp    = (const float*)d_in[26];

    float* ws = (float*)d_ws;
    float* out = (float*)d_out;

    {   // 1) prep + xtpad (merged)
        prep_kernel<<<256 + PREP_BLK, 256, 0, stream>>>(
            x,
            w3, b3, dw3, g3, be3, m3, v3,
            w5, b5, dw5, g5, be5, m5, v5,
            w7, b7, dw7, g7, be7, m7, v7,
            wpw, gp, bp, mp, vp, ws);
    }
    {   // 2) fully fused offconv + sampling + depthwise + pwconv
        dim3 grid(256, 1, Bb);
        mega_kernel<<<grid, 256, 0, stream>>>(ws, out);
    }
}

// Round 11
// 174.933 us; speedup vs baseline: 3.5838x; 1.0111x over previous
//
#include <hip/hip_runtime.h>
#include <hip/hip_fp16.h>
#include <math.h>

typedef unsigned short u16;
typedef _Float16 f16x8 __attribute__((ext_vector_type(8)));
typedef float f32x4 __attribute__((ext_vector_type(4)));

#define HWp 4096
#define Cc 96
#define Bb 4
#define Oo 192
#define C3 288

// ---------- fp32 workspace region (float offsets) ----------
#define OFF_WDWT  0           // [3][49][96]
#define OFF_BCAT  14112       // [192]
#define OFF_SBR   14304       // [288]
#define OFF_HBR   14592       // [288]
#define OFF_SPW   14880       // [192]
#define OFF_HPW   15072       // [192]
#define FP32_END  15264
// ---------- f16 region (u16 offsets, base = ws + FP32_END) ----------
#define BF_XTPAD  0           // [4][66][66][96]
#define BF_WOF    1672704     // 12 frag x 27 step x 64 lane x 8
#define BF_WPW    1838592     // 12 frag x 9 step x 64 lane x 8

__device__ __forceinline__ u16 f2h(float f) { return __half_as_ushort(__float2half(f)); }
__device__ __forceinline__ unsigned h2u(__half2 h) { union { __half2 h; unsigned u; } t; t.h = h; return t.u; }
__device__ __forceinline__ __half2 u2h(unsigned u) { union { __half2 h; unsigned u; } t; t.u = u; return t.h; }

#define PREP_N (165888 + 55296 + 14112 + 192 + 288 + 288 + 192 + 192 + 24960)
#define PREP_BLK ((PREP_N + 255) / 256)

// ---------------- prep + xtpad merged ----------------
__global__ __launch_bounds__(256) void prep_kernel(
    const float* __restrict__ x,
    const float* __restrict__ w3, const float* __restrict__ b3, const float* __restrict__ dw3,
    const float* __restrict__ g3, const float* __restrict__ be3, const float* __restrict__ m3, const float* __restrict__ v3,
    const float* __restrict__ w5, const float* __restrict__ b5, const float* __restrict__ dw5,
    const float* __restrict__ g5, const float* __restrict__ be5, const float* __restrict__ m5, const float* __restrict__ v5,
    const float* __restrict__ w7, const float* __restrict__ b7, const float* __restrict__ dw7,
    const float* __restrict__ g7, const float* __restrict__ be7, const float* __restrict__ m7, const float* __restrict__ v7,
    const float* __restrict__ wpw,
    const float* __restrict__ gp, const float* __restrict__ bp, const float* __restrict__ mp, const float* __restrict__ vp,
    float* __restrict__ ws)
{
    __shared__ u16 sT[64 * 104];
    u16* bf = (u16*)(ws + FP32_END);
    const int tid = threadIdx.x;

    if (blockIdx.x < 256) {                 // ---- xtpad interior ----
        const int b = blockIdx.x >> 6, h = blockIdx.x & 63;
        const float* xb = x + (((size_t)b * Cc) << 12) + (h << 6);
#pragma unroll
        for (int it = 0; it < 24; ++it) {
            int j = tid + it * 256;
            int c = j >> 6, p = j & 63;
            sT[p * 104 + c] = f2h(xb[((size_t)c << 12) + p]);
        }
        __syncthreads();
        u16* dst = bf + BF_XTPAD + ((size_t)(b * 66 + h + 1) * 66 + 1) * 96;
#pragma unroll
        for (int it = 0; it < 6; ++it) {
            int j = tid + it * 256;
            int pos = j / 24, c4 = j % 24;
            const u16* s = &sT[pos * 104 + c4 * 4];
            *(uint2*)(dst + pos * 96 + c4 * 4) = make_uint2(
                (unsigned)s[0] | ((unsigned)s[1] << 16),
                (unsigned)s[2] | ((unsigned)s[3] << 16));
        }
        return;
    }

    int i = (blockIdx.x - 256) * 256 + tid;
    if (i < 165888) {                       // WOF frag-linear f16
        int f = i / 13824, r = i % 13824;
        int s = r >> 9, l = r & 511;
        int lane = l >> 3, j = l & 7;
        int o = f * 16 + (lane & 15);
        int k = s * 32 + (lane >> 4) * 8 + j;
        int tap = k / 96, c = k % 96;
        float v = 0.f;
        if (o < 18)       v = w3[o * 864 + c * 9 + tap];
        else if (o < 68)  v = w5[(o - 18) * 864 + c * 9 + tap];
        else if (o < 166) v = w7[(o - 68) * 864 + c * 9 + tap];
        bf[BF_WOF + i] = f2h(v);
        return;
    }
    int j = i - 165888;
    if (j < 55296) {                        // WPW frag-linear f16
        int f = j / 4608, r = j % 4608;
        int s = r >> 9, l = r & 511;
        int lane = l >> 3, jj = l & 7;
        int o = f * 16 + (lane & 15);
        int k = s * 32 + (lane >> 4) * 8 + jj;
        bf[BF_WPW + j] = f2h(wpw[o * C3 + k]);
        return;
    }
    j -= 55296;
    if (j < 14112) {                        // wdwT [3][49][96] fp32
        int ksel = j / 4704, rem = j % 4704;
        int t = rem / 96, c = rem % 96;
        int K2 = (ksel == 0) ? 9 : (ksel == 1) ? 25 : 49;
        const float* dw = (ksel == 0) ? dw3 : (ksel == 1) ? dw5 : dw7;
        ws[OFF_WDWT + j] = (t < K2) ? dw[c * K2 + t] : 0.f;
        return;
    }
    j -= 14112;
    if (j < 192) {                          // bcat
        float v = 0.f;
        if (j < 18)       v = b3[j];
        else if (j < 68)  v = b5[j - 18];
        else if (j < 166) v = b7[j - 68];
        ws[OFF_BCAT + j] = v;
        return;
    }
    j -= 192;
    if (j < C3) {                           // sbr
        int ks = j / Cc, c = j % Cc;
        const float* g = (ks == 0) ? g3 : (ks == 1) ? g5 : g7;
        const float* v = (ks == 0) ? v3 : (ks == 1) ? v5 : v7;
        ws[OFF_SBR + j] = g[c] / sqrtf(v[c] + 1e-5f);
        return;
    }
    j -= C3;
    if (j < C3) {                           // hbr
        int ks = j / Cc, c = j % Cc;
        const float* g = (ks == 0) ? g3 : (ks == 1) ? g5 : g7;
        const float* v = (ks == 0) ? v3 : (ks == 1) ? v5 : v7;
        const float* be = (ks == 0) ? be3 : (ks == 1) ? be5 : be7;
        const float* m = (ks == 0) ? m3 : (ks == 1) ? m5 : m7;
        float inv = g[c] / sqrtf(v[c] + 1e-5f);
        ws[OFF_HBR + j] = be[c] - m[c] * inv;
        return;
    }
    j -= C3;
    if (j < Oo) { ws[OFF_SPW + j] = gp[j] / sqrtf(vp[j] + 1e-5f); return; }
    j -= Oo;
    if (j < Oo) {
        float inv = gp[j] / sqrtf(vp[j] + 1e-5f);
        ws[OFF_HPW + j] = bp[j] - mp[j] * inv;
        return;
    }
    j -= Oo;
    if (j < 24960) {                        // halo zero
        int c4 = j % 24, rem = j / 24;
        int cell = rem % 260, bb = rem / 260;
        int row, col;
        if (cell < 66)       { row = 0;  col = cell; }
        else if (cell < 132) { row = 65; col = cell - 66; }
        else if (cell < 196) { row = cell - 132 + 1; col = 0; }
        else                 { row = cell - 196 + 1; col = 65; }
        u16* dst = bf + BF_XTPAD + ((size_t)(bb * 66 + row) * 66 + col) * 96 + c4 * 4;
        *(uint2*)dst = make_uint2(0u, 0u);
        return;
    }
}

// ---------------- mega kernel: offconv -> sampling -> depthwise -> pwconv, fully fused ----------------
// XCD-swizzled 1-D grid: xcd = bx&7 serves batch b = xcd>>1 only, so the batch's
// 3.16 MB f16 image stays resident in that XCD's 4 MiB L2 (gathers L2-served, not LLC).
__global__ __launch_bounds__(256, 4) void mega_kernel(
    const float* __restrict__ ws, float* __restrict__ out)
{
    __shared__ uint4 regA[1328];           // 21248 B
    __shared__ float regB[3072];           // 12288 B
    u16* sX = (u16*)regA;
    uint4* sWI = regA;
    float* soff = regB;
    u16* ytile = (u16*)regB;

    const u16* bf = (const u16*)(ws + FP32_END);
    const u16* xp = bf + BF_XTPAD;
    const int tid = threadIdx.x;
    const int lane = tid & 63, wid = tid >> 6;
    const int lane15 = lane & 15, quad = lane >> 4;

    // XCD-aware swizzle: 1024 blocks -> (batch, tile)
    const int bx = blockIdx.x;
    const int xcd = bx & 7;
    const int b = xcd >> 1;                       // 2 XCDs per batch
    const int tile = ((bx >> 3) << 1) + (xcd & 1); // 0..255, sequential rows per XCD
    const int p0 = tile * 16;
    const int h = p0 >> 6;                 // image row
    const int w0 = p0 & 63;                // start col (0/16/32/48)

    // ---- phase 1: load 3-row x 18-col patch into sX ----
    {
        const u16* src = xp + ((size_t)(b * 66 + h) * 66 + w0) * 96;
        for (int j = tid; j < 1296; j += 256) {       // 3*18*24 uint2 chunks
            int r = j / 432;
            int rem = j % 432;
            int col = rem / 24, c4 = rem % 24;
            uint2 v = *(const uint2*)(src + ((size_t)(r * 66 + col)) * 96 + c4 * 4);
            *(uint2*)(&sX[(r * 18 + col) * 104 + c4 * 4]) = v;
        }
    }
    __syncthreads();

    // ---- phase 2: offset conv MFMA (M=192 as 12 frags / 4 waves, N=16, K=864) ----
    {
        const u16* wof = bf + BF_WOF;
        f32x4 acc[3];
#pragma unroll
        for (int ff = 0; ff < 3; ++ff) acc[ff] = (f32x4){0.f, 0.f, 0.f, 0.f};
#pragma unroll
        for (int tap = 0; tap < 9; ++tap) {
            const int ky2 = tap / 3, kx2 = tap % 3;
            const u16* brow = &sX[(ky2 * 18 + kx2 + lane15) * 104 + quad * 8];
#pragma unroll
            for (int cc = 0; cc < 3; ++cc) {
                f16x8 bb = *(const f16x8*)(brow + cc * 32);
                const int s = tap * 3 + cc;
#pragma unroll
                for (int ff = 0; ff < 3; ++ff) {
                    const int f = wid * 3 + ff;
                    f16x8 a = *(const f16x8*)(wof + ((size_t)(f * 27 + s) * 64 + lane) * 8);
                    acc[ff] = __builtin_amdgcn_mfma_f32_16x16x32_f16(a, bb, acc[ff], 0, 0, 0);
                }
            }
        }
        const float* bcat = ws + OFF_BCAT;
#pragma unroll
        for (int ff = 0; ff < 3; ++ff) {
#pragma unroll
            for (int r = 0; r < 4; ++r) {
                int co = (wid * 3 + ff) * 16 + quad * 4 + r;
                soff[co * 16 + lane15] = acc[ff][r] + bcat[co];
            }
        }
    }
    __syncthreads();   // sX reads done; soff complete

    // ---- phase 3: bilinear weight/index table (83 taps x 16 pos) -> sWI (clobbers sX) ----
    for (int i = tid; i < 1328; i += 256) {
        int gt = i >> 4, q = i & 15;
        int K, K2, R, tb, t;
        if (gt < 9)       { K = 3; K2 = 9;  R = 1; tb = 0;  t = gt; }
        else if (gt < 34) { K = 5; K2 = 25; R = 2; tb = 18; t = gt - 9; }
        else              { K = 7; K2 = 49; R = 3; tb = 68; t = gt - 34; }
        int ky = t / K - R, kx = t % K - R;
        float dy = soff[(tb + t) * 16 + q];
        float dx = soff[(tb + K2 + t) * 16 + q];
        float py = fminf(fmaxf((float)(h + ky) + dy, 0.f), 63.f);
        float px = fminf(fmaxf((float)(w0 + q + kx) + dx, 0.f), 63.f);
        float fy = floorf(py), fx = floorf(px);
        int y0 = (int)fy, x0 = (int)fx;
        float wy = py - fy, wx = px - fx;
        int y1 = min(y0 + 1, 63), x1 = min(x0 + 1, 63);
        float w11 = wy * wx;
        float w10 = wy - w11;
        float w01 = wx - w11;
        float w00 = 1.f - wy - wx + w11;
        unsigned wA = h2u(__floats2half2_rn(w00, w01));
        unsigned wB = h2u(__floats2half2_rn(w10, w11));
        unsigned o00 = (unsigned)((y0 + 1) * 66 + (x0 + 1)) * 192u;   // byte offset
        unsigned d01 = (unsigned)(x1 - x0) * 192u;
        unsigned d10 = (unsigned)(y1 - y0) * 12672u;
        sWI[i] = make_uint4(wA, wB, o00, d01 | (d10 << 16));
    }
    __syncthreads();   // soff consumed; sWI ready

    // ---- phase 4: gather + depthwise + BN + ReLU -> ytile (clobbers soff) ----
    if (tid < 192) {
        const int c8 = tid % 12;
        const int q  = tid / 12;            // 0..15
        const int c = c8 * 8;
        const u16* xh = xp + (size_t)b * 66 * 66 * 96;
        const char* xcb = (const char*)xh + c * 2;

#pragma unroll
        for (int seg = 0; seg < 3; ++seg) {
            const int g0 = (seg == 0) ? 0 : (seg == 1) ? 9 : 34;
            const int g1 = (seg == 0) ? 9 : (seg == 1) ? 34 : 83;
            const float* wdT = ws + OFF_WDWT + seg * 4704 + c;
            float acc[8];
#pragma unroll
            for (int k = 0; k < 8; ++k) acc[k] = 0.f;

            for (int gt = g0; gt < g1; ++gt) {
                const uint4 e = sWI[(gt << 4) + q];
                const __half2 wAh = u2h(e.x), wBh = u2h(e.y);
                const __half2 w00b = __low2half2(wAh), w01b = __high2half2(wAh);
                const __half2 w10b = __low2half2(wBh), w11b = __high2half2(wBh);
                const unsigned d01 = e.w & 0xffffu, d10 = e.w >> 16;
                const uint4 u00 = *(const uint4*)(xcb + e.z);
                const uint4 u01 = *(const uint4*)(xcb + e.z + d01);
                const uint4 u10 = *(const uint4*)(xcb + e.z + d10);
                const uint4 u11 = *(const uint4*)(xcb + e.z + d10 + d01);
                const float4 wda = *(const float4*)(wdT + (gt - g0) * 96);
                const float4 wdb = *(const float4*)(wdT + (gt - g0) * 96 + 4);
                const unsigned a00[4] = {u00.x, u00.y, u00.z, u00.w};
                const unsigned a01[4] = {u01.x, u01.y, u01.z, u01.w};
                const unsigned a10[4] = {u10.x, u10.y, u10.z, u10.w};
                const unsigned a11[4] = {u11.x, u11.y, u11.z, u11.w};
                const float wd[8] = {wda.x, wda.y, wda.z, wda.w, wdb.x, wdb.y, wdb.z, wdb.w};
#pragma unroll
                for (int d = 0; d < 4; ++d) {
                    __half2 v = __hmul2(w00b, u2h(a00[d]));
                    v = __hfma2(w01b, u2h(a01[d]), v);
                    v = __hfma2(w10b, u2h(a10[d]), v);
                    v = __hfma2(w11b, u2h(a11[d]), v);
                    acc[2 * d]     = fmaf(wd[2 * d],     __low2float(v),  acc[2 * d]);
                    acc[2 * d + 1] = fmaf(wd[2 * d + 1], __high2float(v), acc[2 * d + 1]);
                }
            }

            const int cb = seg * Cc + c;
            const float4 sa = *(const float4*)(ws + OFF_SBR + cb);
            const float4 sb = *(const float4*)(ws + OFF_SBR + cb + 4);
            const float4 ha = *(const float4*)(ws + OFF_HBR + cb);
            const float4 hb = *(const float4*)(ws + OFF_HBR + cb + 4);
            const float ss[8] = {sa.x, sa.y, sa.z, sa.w, sb.x, sb.y, sb.z, sb.w};
            const float hh8[8] = {ha.x, ha.y, ha.z, ha.w, hb.x, hb.y, hb.z, hb.w};
            unsigned rr[4];
#pragma unroll
            for (int d = 0; d < 4; ++d) {
                float lo = fmaxf(fmaf(acc[2 * d],     ss[2 * d],     hh8[2 * d]),     0.f);
                float hi = fmaxf(fmaf(acc[2 * d + 1], ss[2 * d + 1], hh8[2 * d + 1]), 0.f);
                rr[d] = h2u(__floats2half2_rn(lo, hi));
            }
            *(uint4*)(ytile + q * 296 + cb) = make_uint4(rr[0], rr[1], rr[2], rr[3]);
        }
    }
    __syncthreads();   // sWI consumed; ytile ready

    // ---- phase 5: pointwise MFMA (M=192 as 12 frags / 4 waves, N=16, K=288) + BN + ReLU ----
    {
        const u16* wpw = bf + BF_WPW;
        f32x4 acc[3];
#pragma unroll
        for (int ff = 0; ff < 3; ++ff) acc[ff] = (f32x4){0.f, 0.f, 0.f, 0.f};
        const u16* brow = &ytile[lane15 * 296 + quad * 8];
#pragma unroll
        for (int s = 0; s < 9; ++s) {
            f16x8 bb = *(const f16x8*)(brow + s * 32);
#pragma unroll
            for (int ff = 0; ff < 3; ++ff) {
                const int f = wid * 3 + ff;
                f16x8 a = *(const f16x8*)(wpw + ((size_t)(f * 9 + s) * 64 + lane) * 8);
                acc[ff] = __builtin_amdgcn_mfma_f32_16x16x32_f16(a, bb, acc[ff], 0, 0, 0);
            }
        }
        const float* spw = ws + OFF_SPW;
        const float* hpw = ws + OFF_HPW;
        const int p = p0 + lane15;
#pragma unroll
        for (int ff = 0; ff < 3; ++ff) {
#pragma unroll
            for (int r = 0; r < 4; ++r) {
                int o = (wid * 3 + ff) * 16 + quad * 4 + r;
                out[(((size_t)(b * Oo + o)) << 12) + p] =
                    fmaxf(fmaf(acc[ff][r], spw[o], hpw[o]), 0.f);
            }
        }
    }
}

extern "C" void kernel_launch(void* const* d_in, const int* in_sizes, int n_in,
                              void* d_out, int out_size, void* d_ws, size_t ws_size,
                              hipStream_t stream)
{
    const float* x     = (const float*)d_in[0];
    const float* w3    = (const float*)d_in[1];
    const float* b3    = (const float*)d_in[2];
    const float* dw3   = (const float*)d_in[3];
    const float* g3    = (const float*)d_in[4];
    const float* be3   = (const float*)d_in[5];
    const float* m3    = (const float*)d_in[6];
    const float* v3    = (const float*)d_in[7];
    const float* w5    = (const float*)d_in[8];
    const float* b5    = (const float*)d_in[9];
    const float* dw5   = (const float*)d_in[10];
    const float* g5    = (const float*)d_in[11];
    const float* be5   = (const float*)d_in[12];
    const float* m5    = (const float*)d_in[13];
    const float* v5    = (const float*)d_in[14];
    const float* w7    = (const float*)d_in[15];
    const float* b7    = (const float*)d_in[16];
    const float* dw7   = (const float*)d_in[17];
    const float* g7    = (const float*)d_in[18];
    const float* be7   = (const float*)d_in[19];
    const float* m7    = (const float*)d_in[20];
    const float* v7    = (const float*)d_in[21];
    const float* wpw   = (const float*)d_in[22];
    const float* gp    = (const float*)d_in[23];
    const float* bp    = (const float*)d_in[24];
    const float* mp    = (const float*)d_in[25];
    const float* vp    = (const float*)d_in[26];

    float* ws = (float*)d_ws;
    float* out = (float*)d_out;

    {   // 1) prep + xtpad (merged)
        prep_kernel<<<256 + PREP_BLK, 256, 0, stream>>>(
            x,
            w3, b3, dw3, g3, be3, m3, v3,
            w5, b5, dw5, g5, be5, m5, v5,
            w7, b7, dw7, g7, be7, m7, v7,
            wpw, gp, bp, mp, vp, ws);
    }
    {   // 2) fully fused pipeline, XCD-swizzled 1-D grid
        mega_kernel<<<1024, 256, 0, stream>>>(ws, out);
    }
}